// Round 1
// baseline (1691.412 us; speedup 1.0000x reference)
//
#include <hip/hip_runtime.h>
#include <math.h>

#define DD 64
#define CHUNK 1024

static inline int divup(int a, int b){ return (a + b - 1) / b; }

// --- histogram of row (for degree) and col (for CSR) ---
__global__ void hist_k(const int* __restrict__ edg, int* __restrict__ rowcnt,
                       int* __restrict__ colcnt, int E){
  int e = blockIdx.x * 256 + threadIdx.x;
  if (e < E){
    atomicAdd(&rowcnt[edg[e]], 1);      // edgidx[0] = rows
    atomicAdd(&colcnt[edg[E + e]], 1);  // edgidx[1] = cols
  }
}

// dinv = (rowcnt + 2)^-1/2   (improved=True self loops, weight 2)
__global__ void dinv_k(const int* __restrict__ rowcnt, float* __restrict__ dinv, int N){
  int i = blockIdx.x * 256 + threadIdx.x;
  if (i < N) dinv[i] = 1.0f / sqrtf((float)rowcnt[i] + 2.0f);
}

// --- 3-kernel exclusive scan of colcnt -> offsets (N+1) ---
__global__ void scan1_k(const int* __restrict__ cnt, int* __restrict__ bsum, int N){
  __shared__ int sh[256];
  int t = threadIdx.x;
  int base = blockIdx.x * CHUNK + t * 4;
  int s = 0;
  #pragma unroll
  for (int j = 0; j < 4; j++){ int g = base + j; if (g < N) s += cnt[g]; }
  sh[t] = s; __syncthreads();
  for (int off = 128; off > 0; off >>= 1){
    if (t < off) sh[t] += sh[t + off];
    __syncthreads();
  }
  if (t == 0) bsum[blockIdx.x] = sh[0];
}

__global__ void scan2_k(const int* __restrict__ bsum, int* __restrict__ bpre, int NB){
  __shared__ int sh[128];
  int t = threadIdx.x;
  int v = (t < NB) ? bsum[t] : 0;
  sh[t] = v; __syncthreads();
  for (int off = 1; off < 128; off <<= 1){
    int x = (t >= off) ? sh[t - off] : 0;
    __syncthreads();
    sh[t] += x;
    __syncthreads();
  }
  if (t < NB) bpre[t] = sh[t] - v;   // exclusive
}

__global__ void scan3_k(const int* __restrict__ cnt, const int* __restrict__ bpre,
                        int* __restrict__ offsets, int N){
  __shared__ int sh[256];
  int t = threadIdx.x, b = blockIdx.x;
  int base = b * CHUNK + t * 4;
  int v[4]; int s = 0;
  #pragma unroll
  for (int j = 0; j < 4; j++){ int g = base + j; v[j] = (g < N) ? cnt[g] : 0; s += v[j]; }
  sh[t] = s; __syncthreads();
  for (int off = 1; off < 256; off <<= 1){
    int x = (t >= off) ? sh[t - off] : 0;
    __syncthreads();
    sh[t] += x;
    __syncthreads();
  }
  int run = sh[t] - s + bpre[b];   // exclusive prefix at base
  #pragma unroll
  for (int j = 0; j < 4; j++){
    int g = base + j;
    if (g <= N) offsets[g] = run;
    run += v[j];
  }
}

// --- scatter edges into CSR (by col), weight = dinv[row]*dinv[col] ---
__global__ void scatter_k(const int* __restrict__ edg, const float* __restrict__ dinv,
                          const int* __restrict__ offsets, int* __restrict__ cursor,
                          int* __restrict__ csr_src, float* __restrict__ csr_w, int E){
  int e = blockIdx.x * 256 + threadIdx.x;
  if (e < E){
    int r = edg[e];
    int c = edg[E + e];
    int pos = offsets[c] + atomicAdd(&cursor[c], 1);
    csr_src[pos] = r;
    csr_w[pos] = dinv[r] * dinv[c];
  }
}

// --- fused aggregation of two feature matrices: one wave per node, lane = feature ---
__global__ void agg2_k(const float* __restrict__ X, const float* __restrict__ H,
                       const int* __restrict__ offsets, const int* __restrict__ src,
                       const float* __restrict__ w, const float* __restrict__ dinv,
                       float* __restrict__ AX, float* __restrict__ AH, int N){
  int wid = (blockIdx.x * blockDim.x + threadIdx.x) >> 6;
  int lane = threadIdx.x & 63;
  if (wid >= N) return;
  float dv = dinv[wid];
  float selfw = 2.0f * dv * dv;
  size_t me = (size_t)wid * DD + lane;
  float ax = selfw * X[me];
  float ah = selfw * H[me];
  int s0 = offsets[wid], s1 = offsets[wid + 1];
  for (int e = s0; e < s1; ++e){
    int sidx = src[e];
    float we = w[e];
    size_t o = (size_t)sidx * DD + lane;
    ax += we * X[o];
    ah += we * H[o];
  }
  AX[me] = ax;
  AH[me] = ah;
}

__global__ void agg1_k(const float* __restrict__ X,
                       const int* __restrict__ offsets, const int* __restrict__ src,
                       const float* __restrict__ w, const float* __restrict__ dinv,
                       float* __restrict__ AX, int N){
  int wid = (blockIdx.x * blockDim.x + threadIdx.x) >> 6;
  int lane = threadIdx.x & 63;
  if (wid >= N) return;
  float dv = dinv[wid];
  float selfw = 2.0f * dv * dv;
  size_t me = (size_t)wid * DD + lane;
  float ax = selfw * X[me];
  int s0 = offsets[wid], s1 = offsets[wid + 1];
  for (int e = s0; e < s1; ++e){
    int sidx = src[e];
    float we = w[e];
    ax += we * X[(size_t)sidx * DD + lane];
  }
  AX[me] = ax;
}

// --- fused gate GEMM: z, r*h, t1 = Ax@Wxh + bxh + bhh.  Wave = 8 nodes, lane = dout ---
__global__ void gate_k(const float* __restrict__ AX, const float* __restrict__ AH,
                       const float* __restrict__ Hh,
                       const float* __restrict__ Wxz, const float* __restrict__ Whz,
                       const float* __restrict__ Wxr, const float* __restrict__ Whr,
                       const float* __restrict__ Wxh,
                       const float* __restrict__ bxz, const float* __restrict__ bhz,
                       const float* __restrict__ bxr, const float* __restrict__ bhr,
                       const float* __restrict__ bxh, const float* __restrict__ bhh,
                       float* __restrict__ zb, float* __restrict__ rhb,
                       float* __restrict__ t1b, int N){
  const int M = 8;
  int wid = (blockIdx.x * blockDim.x + threadIdx.x) >> 6;
  int lane = threadIdx.x & 63;
  long base = (long)wid * M;
  if (base >= N) return;
  float ax[M], ah[M], hv[M], acc[M];
  #pragma unroll
  for (int m = 0; m < M; m++){
    long n = (base + m < N) ? base + m : N - 1;
    ax[m] = AX[n * DD + lane];
    ah[m] = AH[n * DD + lane];
    hv[m] = Hh[n * DD + lane];
  }
  // ---- z = sigmoid(ax@Wxz + ah@Whz + bxz + bhz) ----
  float bz = bxz[lane] + bhz[lane];
  #pragma unroll
  for (int m = 0; m < M; m++) acc[m] = bz;
  for (int k = 0; k < DD; k++){
    float wv = Wxz[k * DD + lane];
    #pragma unroll
    for (int m = 0; m < M; m++) acc[m] += __shfl(ax[m], k) * wv;
  }
  for (int k = 0; k < DD; k++){
    float wv = Whz[k * DD + lane];
    #pragma unroll
    for (int m = 0; m < M; m++) acc[m] += __shfl(ah[m], k) * wv;
  }
  float zv[M];
  #pragma unroll
  for (int m = 0; m < M; m++) zv[m] = 1.0f / (1.0f + __expf(-acc[m]));
  // ---- r = sigmoid(ax@Wxr + ah@Whr + bxr + bhr) ----
  float br = bxr[lane] + bhr[lane];
  #pragma unroll
  for (int m = 0; m < M; m++) acc[m] = br;
  for (int k = 0; k < DD; k++){
    float wv = Wxr[k * DD + lane];
    #pragma unroll
    for (int m = 0; m < M; m++) acc[m] += __shfl(ax[m], k) * wv;
  }
  for (int k = 0; k < DD; k++){
    float wv = Whr[k * DD + lane];
    #pragma unroll
    for (int m = 0; m < M; m++) acc[m] += __shfl(ah[m], k) * wv;
  }
  #pragma unroll
  for (int m = 0; m < M; m++){
    long n = base + m;
    if (n < N){
      float rr = 1.0f / (1.0f + __expf(-acc[m]));
      zb[n * DD + lane] = zv[m];
      rhb[n * DD + lane] = rr * hv[m];
    }
  }
  // ---- t1 = ax@Wxh + bxh + bhh ----
  float bt = bxh[lane] + bhh[lane];
  #pragma unroll
  for (int m = 0; m < M; m++) acc[m] = bt;
  for (int k = 0; k < DD; k++){
    float wv = Wxh[k * DD + lane];
    #pragma unroll
    for (int m = 0; m < M; m++) acc[m] += __shfl(ax[m], k) * wv;
  }
  #pragma unroll
  for (int m = 0; m < M; m++){
    long n = base + m;
    if (n < N) t1b[n * DD + lane] = acc[m];
  }
}

// --- output: h_t = tanh(t1 + Arh@Whh), ho = z*h + (1-z)*h_t, write both copies ---
__global__ void out_k(const float* __restrict__ Arh, const float* __restrict__ t1b,
                      const float* __restrict__ zb, const float* __restrict__ Hh,
                      const float* __restrict__ Whh,
                      float* __restrict__ o1, float* __restrict__ o2, int N){
  const int M = 8;
  int wid = (blockIdx.x * blockDim.x + threadIdx.x) >> 6;
  int lane = threadIdx.x & 63;
  long base = (long)wid * M;
  if (base >= N) return;
  float ar[M], acc[M];
  #pragma unroll
  for (int m = 0; m < M; m++){
    long n = (base + m < N) ? base + m : N - 1;
    ar[m] = Arh[n * DD + lane];
    acc[m] = t1b[n * DD + lane];
  }
  for (int k = 0; k < DD; k++){
    float wv = Whh[k * DD + lane];
    #pragma unroll
    for (int m = 0; m < M; m++) acc[m] += __shfl(ar[m], k) * wv;
  }
  #pragma unroll
  for (int m = 0; m < M; m++){
    long n = base + m;
    if (n < N){
      float ht = tanhf(acc[m]);
      float z = zb[n * DD + lane];
      float hval = Hh[n * DD + lane];
      float ho = z * hval + (1.0f - z) * ht;
      o1[n * DD + lane] = ho;
      o2[n * DD + lane] = ho;
    }
  }
}

extern "C" void kernel_launch(void* const* d_in, const int* in_sizes, int n_in,
                              void* d_out, int out_size, void* d_ws, size_t ws_size,
                              hipStream_t stream){
  const float* inp = (const float*)d_in[0];
  const float* h   = (const float*)d_in[1];
  const int*   edg = (const int*)d_in[2];
  const float* Wxz = (const float*)d_in[3];
  const float* Whz = (const float*)d_in[4];
  const float* Wxr = (const float*)d_in[5];
  const float* Whr = (const float*)d_in[6];
  const float* Wxh = (const float*)d_in[7];
  const float* Whh = (const float*)d_in[8];
  const float* bxz = (const float*)d_in[9];
  const float* bhz = (const float*)d_in[10];
  const float* bxr = (const float*)d_in[11];
  const float* bhr = (const float*)d_in[12];
  const float* bxh = (const float*)d_in[13];
  const float* bhh = (const float*)d_in[14];
  float* out = (float*)d_out;

  const int ND = in_sizes[0];
  const int N  = ND / DD;
  const int E  = in_sizes[2] / 2;
  const int L  = in_sizes[1] / ND;

  // workspace carve (all 256B-aligned)
  char* p = (char*)d_ws;
  auto alloc = [&](size_t bytes) -> void* {
    void* r = (void*)p;
    p += ((bytes + 255) / 256) * 256;
    return r;
  };
  int*   rowcnt  = (int*)alloc((size_t)3 * N * 4);  // rowcnt | colcnt | cursor contiguous
  int*   colcnt  = rowcnt + N;
  int*   cursor  = colcnt + N;
  int*   offsets = (int*)alloc((size_t)(N + 1) * 4);
  int*   bsum    = (int*)alloc(128 * 4);
  int*   bpre    = (int*)alloc(128 * 4);
  float* dinv    = (float*)alloc((size_t)N * 4);
  int*   csr_src = (int*)alloc((size_t)E * 4);
  float* csr_w   = (float*)alloc((size_t)E * 4);
  float* Ax      = (float*)alloc((size_t)ND * 4);
  float* Ah      = (float*)alloc((size_t)ND * 4);
  float* Arh     = (float*)alloc((size_t)ND * 4);
  float* zb      = (float*)alloc((size_t)ND * 4);
  float* rhb     = (float*)alloc((size_t)ND * 4);
  float* t1b     = (float*)alloc((size_t)ND * 4);

  hipMemsetAsync(rowcnt, 0, (size_t)3 * N * 4, stream);

  const int NB = divup(N, CHUNK);
  hist_k<<<divup(E, 256), 256, 0, stream>>>(edg, rowcnt, colcnt, E);
  dinv_k<<<divup(N, 256), 256, 0, stream>>>(rowcnt, dinv, N);
  scan1_k<<<NB, 256, 0, stream>>>(colcnt, bsum, N);
  scan2_k<<<1, 128, 0, stream>>>(bsum, bpre, NB);
  scan3_k<<<NB, 256, 0, stream>>>(colcnt, bpre, offsets, N);
  scatter_k<<<divup(E, 256), 256, 0, stream>>>(edg, dinv, offsets, cursor, csr_src, csr_w, E);

  const int aggBlocks = divup(N, 4);    // 4 waves (nodes) per 256-thread block
  const int gBlocks   = divup(N, 32);   // 4 waves * 8 nodes per block

  for (int l = 0; l < L; l++){
    const float* X  = (l == 0) ? inp : out + (size_t)(l - 1) * ND;
    const float* Hh = h + (size_t)l * ND;
    agg2_k<<<aggBlocks, 256, 0, stream>>>(X, Hh, offsets, csr_src, csr_w, dinv, Ax, Ah, N);
    gate_k<<<gBlocks, 256, 0, stream>>>(Ax, Ah, Hh,
        Wxz + (size_t)l * DD * DD, Whz + (size_t)l * DD * DD,
        Wxr + (size_t)l * DD * DD, Whr + (size_t)l * DD * DD,
        Wxh + (size_t)l * DD * DD,
        bxz + (size_t)l * DD, bhz + (size_t)l * DD,
        bxr + (size_t)l * DD, bhr + (size_t)l * DD,
        bxh + (size_t)l * DD, bhh + (size_t)l * DD,
        zb, rhb, t1b, N);
    agg1_k<<<aggBlocks, 256, 0, stream>>>(rhb, offsets, csr_src, csr_w, dinv, Arh, N);
    out_k<<<gBlocks, 256, 0, stream>>>(Arh, t1b, zb, Hh, Whh + (size_t)l * DD * DD,
        out + (size_t)l * ND, out + (size_t)L * ND + (size_t)l * ND, N);
  }
}

// Round 2
// 1478.666 us; speedup vs baseline: 1.1439x; 1.1439x over previous
//
#include <hip/hip_runtime.h>
#include <math.h>

#define DD 64
#define CHUNK 1024

static inline int divup(int a, int b){ return (a + b - 1) / b; }

// --- histogram of row (for degree) and col (for CSR) ---
__global__ void hist_k(const int* __restrict__ edg, int* __restrict__ rowcnt,
                       int* __restrict__ colcnt, int E){
  int e = blockIdx.x * 256 + threadIdx.x;
  if (e < E){
    atomicAdd(&rowcnt[edg[e]], 1);      // edgidx[0] = rows
    atomicAdd(&colcnt[edg[E + e]], 1);  // edgidx[1] = cols
  }
}

// dinv = (rowcnt + 2)^-1/2   (improved=True self loops, weight 2)
__global__ void dinv_k(const int* __restrict__ rowcnt, float* __restrict__ dinv, int N){
  int i = blockIdx.x * 256 + threadIdx.x;
  if (i < N) dinv[i] = 1.0f / sqrtf((float)rowcnt[i] + 2.0f);
}

// --- 3-kernel exclusive scan of colcnt -> offsets (N+1) ---
__global__ void scan1_k(const int* __restrict__ cnt, int* __restrict__ bsum, int N){
  __shared__ int sh[256];
  int t = threadIdx.x;
  int base = blockIdx.x * CHUNK + t * 4;
  int s = 0;
  #pragma unroll
  for (int j = 0; j < 4; j++){ int g = base + j; if (g < N) s += cnt[g]; }
  sh[t] = s; __syncthreads();
  for (int off = 128; off > 0; off >>= 1){
    if (t < off) sh[t] += sh[t + off];
    __syncthreads();
  }
  if (t == 0) bsum[blockIdx.x] = sh[0];
}

__global__ void scan2_k(const int* __restrict__ bsum, int* __restrict__ bpre, int NB){
  __shared__ int sh[128];
  int t = threadIdx.x;
  int v = (t < NB) ? bsum[t] : 0;
  sh[t] = v; __syncthreads();
  for (int off = 1; off < 128; off <<= 1){
    int x = (t >= off) ? sh[t - off] : 0;
    __syncthreads();
    sh[t] += x;
    __syncthreads();
  }
  if (t < NB) bpre[t] = sh[t] - v;   // exclusive
}

__global__ void scan3_k(const int* __restrict__ cnt, const int* __restrict__ bpre,
                        int* __restrict__ offsets, int N){
  __shared__ int sh[256];
  int t = threadIdx.x, b = blockIdx.x;
  int base = b * CHUNK + t * 4;
  int v[4]; int s = 0;
  #pragma unroll
  for (int j = 0; j < 4; j++){ int g = base + j; v[j] = (g < N) ? cnt[g] : 0; s += v[j]; }
  sh[t] = s; __syncthreads();
  for (int off = 1; off < 256; off <<= 1){
    int x = (t >= off) ? sh[t - off] : 0;
    __syncthreads();
    sh[t] += x;
    __syncthreads();
  }
  int run = sh[t] - s + bpre[b];   // exclusive prefix at base
  #pragma unroll
  for (int j = 0; j < 4; j++){
    int g = base + j;
    if (g <= N) offsets[g] = run;
    run += v[j];
  }
}

// --- scatter edges into CSR (by col), weight = dinv[row]*dinv[col] ---
__global__ void scatter_k(const int* __restrict__ edg, const float* __restrict__ dinv,
                          const int* __restrict__ offsets, int* __restrict__ cursor,
                          int* __restrict__ csr_src, float* __restrict__ csr_w, int E){
  int e = blockIdx.x * 256 + threadIdx.x;
  if (e < E){
    int r = edg[e];
    int c = edg[E + e];
    int pos = offsets[c] + atomicAdd(&cursor[c], 1);
    csr_src[pos] = r;
    csr_w[pos] = dinv[r] * dinv[c];
  }
}

// --- fused aggregation of two feature matrices: one wave per node, lane = feature ---
// unroll-by-2 with independent accumulators to keep 2+ gathers in flight
__global__ void agg2_k(const float* __restrict__ X, const float* __restrict__ H,
                       const int* __restrict__ offsets, const int* __restrict__ src,
                       const float* __restrict__ w, const float* __restrict__ dinv,
                       float* __restrict__ AX, float* __restrict__ AH, int N){
  int wid = (blockIdx.x * blockDim.x + threadIdx.x) >> 6;
  int lane = threadIdx.x & 63;
  if (wid >= N) return;
  float dv = dinv[wid];
  float selfw = 2.0f * dv * dv;
  size_t me = (size_t)wid * DD + lane;
  float ax = selfw * X[me];
  float ah = selfw * H[me];
  float ax2 = 0.0f, ah2 = 0.0f;
  int s0 = offsets[wid], s1 = offsets[wid + 1];
  int e = s0;
  for (; e + 2 <= s1; e += 2){
    int sa = src[e], sb = src[e + 1];
    float wa = w[e], wb = w[e + 1];
    size_t oa = (size_t)sa * DD + lane;
    size_t ob = (size_t)sb * DD + lane;
    ax  += wa * X[oa];
    ah  += wa * H[oa];
    ax2 += wb * X[ob];
    ah2 += wb * H[ob];
  }
  if (e < s1){
    int sa = src[e];
    float wa = w[e];
    size_t oa = (size_t)sa * DD + lane;
    ax += wa * X[oa];
    ah += wa * H[oa];
  }
  AX[me] = ax + ax2;
  AH[me] = ah + ah2;
}

__global__ void agg1_k(const float* __restrict__ X,
                       const int* __restrict__ offsets, const int* __restrict__ src,
                       const float* __restrict__ w, const float* __restrict__ dinv,
                       float* __restrict__ AX, int N){
  int wid = (blockIdx.x * blockDim.x + threadIdx.x) >> 6;
  int lane = threadIdx.x & 63;
  if (wid >= N) return;
  float dv = dinv[wid];
  float selfw = 2.0f * dv * dv;
  size_t me = (size_t)wid * DD + lane;
  float ax = selfw * X[me];
  float ax2 = 0.0f;
  int s0 = offsets[wid], s1 = offsets[wid + 1];
  int e = s0;
  for (; e + 2 <= s1; e += 2){
    int sa = src[e], sb = src[e + 1];
    float wa = w[e], wb = w[e + 1];
    ax  += wa * X[(size_t)sa * DD + lane];
    ax2 += wb * X[(size_t)sb * DD + lane];
  }
  if (e < s1){
    ax += w[e] * X[(size_t)src[e] * DD + lane];
  }
  AX[me] = ax + ax2;
}

// ---------------------------------------------------------------------------
// Dense gate kernel, v2: lane = node. Each lane computes its node's full
// output rows. W[k][j] indices are wave-uniform -> s_load + v_fmac(s,v):
// zero shuffles, zero LDS (the v1 kernel was LDS-pipe bound on ds_bpermute).
// Output split into two j-halves (acc[32]) to keep VGPRs ~8 waves/SIMD.
// ---------------------------------------------------------------------------
__global__ __launch_bounds__(256) void gate2_k(
    const float* __restrict__ AX, const float* __restrict__ AH,
    const float* __restrict__ Hh,
    const float* __restrict__ Wxz, const float* __restrict__ Whz,
    const float* __restrict__ Wxr, const float* __restrict__ Whr,
    const float* __restrict__ Wxh,
    const float* __restrict__ bxz, const float* __restrict__ bhz,
    const float* __restrict__ bxr, const float* __restrict__ bhr,
    const float* __restrict__ bxh, const float* __restrict__ bhh,
    float* __restrict__ zb, float* __restrict__ rhb,
    float* __restrict__ t1b, int N)
{
  int node = blockIdx.x * 256 + threadIdx.x;
  int nc = node < N ? node : N - 1;
  const bool wr = node < N;
  const float4* axr = (const float4*)(AX + (size_t)nc * DD);
  const float4* ahr = (const float4*)(AH + (size_t)nc * DD);
  const float4* hr  = (const float4*)(Hh + (size_t)nc * DD);

  // ---- z = sigmoid(ax@Wxz + ah@Whz + b) ----
  #pragma unroll 1
  for (int half = 0; half < 2; half++){
    const int jb = half * 32;
    float acc[32];
    #pragma unroll
    for (int j = 0; j < 32; j++) acc[j] = bxz[jb + j] + bhz[jb + j];
    #pragma unroll 2
    for (int k4 = 0; k4 < 16; k4++){
      float4 a4 = axr[k4];
      float4 h4 = ahr[k4];
      #pragma unroll
      for (int kk = 0; kk < 4; kk++){
        const float xk = kk == 0 ? a4.x : kk == 1 ? a4.y : kk == 2 ? a4.z : a4.w;
        const float hk = kk == 0 ? h4.x : kk == 1 ? h4.y : kk == 2 ? h4.z : h4.w;
        const float* wx = Wxz + (k4 * 4 + kk) * DD + jb;
        const float* wh = Whz + (k4 * 4 + kk) * DD + jb;
        #pragma unroll
        for (int j = 0; j < 32; j++) acc[j] += xk * wx[j] + hk * wh[j];
      }
    }
    if (wr){
      float4* zrow = (float4*)(zb + (size_t)node * DD + jb);
      #pragma unroll
      for (int q = 0; q < 8; q++){
        float4 v;
        v.x = 1.0f / (1.0f + __expf(-acc[4 * q + 0]));
        v.y = 1.0f / (1.0f + __expf(-acc[4 * q + 1]));
        v.z = 1.0f / (1.0f + __expf(-acc[4 * q + 2]));
        v.w = 1.0f / (1.0f + __expf(-acc[4 * q + 3]));
        zrow[q] = v;
      }
    }
  }

  // ---- r = sigmoid(ax@Wxr + ah@Whr + b); store r*h ----
  #pragma unroll 1
  for (int half = 0; half < 2; half++){
    const int jb = half * 32;
    float acc[32];
    #pragma unroll
    for (int j = 0; j < 32; j++) acc[j] = bxr[jb + j] + bhr[jb + j];
    #pragma unroll 2
    for (int k4 = 0; k4 < 16; k4++){
      float4 a4 = axr[k4];
      float4 h4 = ahr[k4];
      #pragma unroll
      for (int kk = 0; kk < 4; kk++){
        const float xk = kk == 0 ? a4.x : kk == 1 ? a4.y : kk == 2 ? a4.z : a4.w;
        const float hk = kk == 0 ? h4.x : kk == 1 ? h4.y : kk == 2 ? h4.z : h4.w;
        const float* wx = Wxr + (k4 * 4 + kk) * DD + jb;
        const float* wh = Whr + (k4 * 4 + kk) * DD + jb;
        #pragma unroll
        for (int j = 0; j < 32; j++) acc[j] += xk * wx[j] + hk * wh[j];
      }
    }
    if (wr){
      float4* rrow = (float4*)(rhb + (size_t)node * DD + jb);
      #pragma unroll
      for (int q = 0; q < 8; q++){
        float4 hv = hr[half * 8 + q];
        float4 v;
        v.x = hv.x / (1.0f + __expf(-acc[4 * q + 0]));
        v.y = hv.y / (1.0f + __expf(-acc[4 * q + 1]));
        v.z = hv.z / (1.0f + __expf(-acc[4 * q + 2]));
        v.w = hv.w / (1.0f + __expf(-acc[4 * q + 3]));
        rrow[q] = v;
      }
    }
  }

  // ---- t1 = ax@Wxh + bxh + bhh ----
  #pragma unroll 1
  for (int half = 0; half < 2; half++){
    const int jb = half * 32;
    float acc[32];
    #pragma unroll
    for (int j = 0; j < 32; j++) acc[j] = bxh[jb + j] + bhh[jb + j];
    #pragma unroll 2
    for (int k4 = 0; k4 < 16; k4++){
      float4 a4 = axr[k4];
      #pragma unroll
      for (int kk = 0; kk < 4; kk++){
        const float xk = kk == 0 ? a4.x : kk == 1 ? a4.y : kk == 2 ? a4.z : a4.w;
        const float* wx = Wxh + (k4 * 4 + kk) * DD + jb;
        #pragma unroll
        for (int j = 0; j < 32; j++) acc[j] += xk * wx[j];
      }
    }
    if (wr){
      float4* trow = (float4*)(t1b + (size_t)node * DD + jb);
      #pragma unroll
      for (int q = 0; q < 8; q++){
        float4 v;
        v.x = acc[4 * q + 0]; v.y = acc[4 * q + 1];
        v.z = acc[4 * q + 2]; v.w = acc[4 * q + 3];
        trow[q] = v;
      }
    }
  }
}

// --- output: h_t = tanh(t1 + Arh@Whh), ho = z*h + (1-z)*h_t, write both copies ---
__global__ __launch_bounds__(256) void out2_k(
    const float* __restrict__ Arh, const float* __restrict__ t1b,
    const float* __restrict__ zb, const float* __restrict__ Hh,
    const float* __restrict__ Whh,
    float* __restrict__ o1, float* __restrict__ o2, int N)
{
  int node = blockIdx.x * 256 + threadIdx.x;
  int nc = node < N ? node : N - 1;
  const bool wr = node < N;
  const float4* arr = (const float4*)(Arh + (size_t)nc * DD);
  const float4* tr  = (const float4*)(t1b + (size_t)nc * DD);
  const float4* zr  = (const float4*)(zb  + (size_t)nc * DD);
  const float4* hr  = (const float4*)(Hh  + (size_t)nc * DD);

  #pragma unroll 1
  for (int half = 0; half < 2; half++){
    const int jb = half * 32;
    float acc[32];
    #pragma unroll
    for (int q = 0; q < 8; q++){
      float4 t4 = tr[half * 8 + q];
      acc[4 * q + 0] = t4.x; acc[4 * q + 1] = t4.y;
      acc[4 * q + 2] = t4.z; acc[4 * q + 3] = t4.w;
    }
    #pragma unroll 2
    for (int k4 = 0; k4 < 16; k4++){
      float4 a4 = arr[k4];
      #pragma unroll
      for (int kk = 0; kk < 4; kk++){
        const float xk = kk == 0 ? a4.x : kk == 1 ? a4.y : kk == 2 ? a4.z : a4.w;
        const float* wx = Whh + (k4 * 4 + kk) * DD + jb;
        #pragma unroll
        for (int j = 0; j < 32; j++) acc[j] += xk * wx[j];
      }
    }
    if (wr){
      float4* o1row = (float4*)(o1 + (size_t)node * DD + jb);
      float4* o2row = (float4*)(o2 + (size_t)node * DD + jb);
      #pragma unroll
      for (int q = 0; q < 8; q++){
        float4 z4 = zr[half * 8 + q];
        float4 h4 = hr[half * 8 + q];
        float4 v;
        float ht0 = tanhf(acc[4 * q + 0]);
        float ht1 = tanhf(acc[4 * q + 1]);
        float ht2 = tanhf(acc[4 * q + 2]);
        float ht3 = tanhf(acc[4 * q + 3]);
        v.x = z4.x * h4.x + (1.0f - z4.x) * ht0;
        v.y = z4.y * h4.y + (1.0f - z4.y) * ht1;
        v.z = z4.z * h4.z + (1.0f - z4.z) * ht2;
        v.w = z4.w * h4.w + (1.0f - z4.w) * ht3;
        o1row[q] = v;
        o2row[q] = v;
      }
    }
  }
}

extern "C" void kernel_launch(void* const* d_in, const int* in_sizes, int n_in,
                              void* d_out, int out_size, void* d_ws, size_t ws_size,
                              hipStream_t stream){
  const float* inp = (const float*)d_in[0];
  const float* h   = (const float*)d_in[1];
  const int*   edg = (const int*)d_in[2];
  const float* Wxz = (const float*)d_in[3];
  const float* Whz = (const float*)d_in[4];
  const float* Wxr = (const float*)d_in[5];
  const float* Whr = (const float*)d_in[6];
  const float* Wxh = (const float*)d_in[7];
  const float* Whh = (const float*)d_in[8];
  const float* bxz = (const float*)d_in[9];
  const float* bhz = (const float*)d_in[10];
  const float* bxr = (const float*)d_in[11];
  const float* bhr = (const float*)d_in[12];
  const float* bxh = (const float*)d_in[13];
  const float* bhh = (const float*)d_in[14];
  float* out = (float*)d_out;

  const int ND = in_sizes[0];
  const int N  = ND / DD;
  const int E  = in_sizes[2] / 2;
  const int L  = in_sizes[1] / ND;

  // workspace carve (all 256B-aligned)
  char* p = (char*)d_ws;
  auto alloc = [&](size_t bytes) -> void* {
    void* r = (void*)p;
    p += ((bytes + 255) / 256) * 256;
    return r;
  };
  int*   rowcnt  = (int*)alloc((size_t)3 * N * 4);  // rowcnt | colcnt | cursor contiguous
  int*   colcnt  = rowcnt + N;
  int*   cursor  = colcnt + N;
  int*   offsets = (int*)alloc((size_t)(N + 1) * 4);
  int*   bsum    = (int*)alloc(128 * 4);
  int*   bpre    = (int*)alloc(128 * 4);
  float* dinv    = (float*)alloc((size_t)N * 4);
  int*   csr_src = (int*)alloc((size_t)E * 4);
  float* csr_w   = (float*)alloc((size_t)E * 4);
  float* Ax      = (float*)alloc((size_t)ND * 4);
  float* Ah      = (float*)alloc((size_t)ND * 4);
  float* Arh     = (float*)alloc((size_t)ND * 4);
  float* zb      = (float*)alloc((size_t)ND * 4);
  float* rhb     = (float*)alloc((size_t)ND * 4);
  float* t1b     = (float*)alloc((size_t)ND * 4);

  hipMemsetAsync(rowcnt, 0, (size_t)3 * N * 4, stream);

  const int NB = divup(N, CHUNK);
  hist_k<<<divup(E, 256), 256, 0, stream>>>(edg, rowcnt, colcnt, E);
  dinv_k<<<divup(N, 256), 256, 0, stream>>>(rowcnt, dinv, N);
  scan1_k<<<NB, 256, 0, stream>>>(colcnt, bsum, N);
  scan2_k<<<1, 128, 0, stream>>>(bsum, bpre, NB);
  scan3_k<<<NB, 256, 0, stream>>>(colcnt, bpre, offsets, N);
  scatter_k<<<divup(E, 256), 256, 0, stream>>>(edg, dinv, offsets, cursor, csr_src, csr_w, E);

  const int aggBlocks = divup(N, 4);    // 4 waves (nodes) per 256-thread block
  const int nBlocks   = divup(N, 256);  // lane = node

  for (int l = 0; l < L; l++){
    const float* X  = (l == 0) ? inp : out + (size_t)(l - 1) * ND;
    const float* Hh = h + (size_t)l * ND;
    agg2_k<<<aggBlocks, 256, 0, stream>>>(X, Hh, offsets, csr_src, csr_w, dinv, Ax, Ah, N);
    gate2_k<<<nBlocks, 256, 0, stream>>>(Ax, Ah, Hh,
        Wxz + (size_t)l * DD * DD, Whz + (size_t)l * DD * DD,
        Wxr + (size_t)l * DD * DD, Whr + (size_t)l * DD * DD,
        Wxh + (size_t)l * DD * DD,
        bxz + (size_t)l * DD, bhz + (size_t)l * DD,
        bxr + (size_t)l * DD, bhr + (size_t)l * DD,
        bxh + (size_t)l * DD, bhh + (size_t)l * DD,
        zb, rhb, t1b, N);
    agg1_k<<<aggBlocks, 256, 0, stream>>>(rhb, offsets, csr_src, csr_w, dinv, Arh, N);
    out2_k<<<nBlocks, 256, 0, stream>>>(Arh, t1b, zb, Hh, Whh + (size_t)l * DD * DD,
        out + (size_t)l * ND, out + (size_t)L * ND + (size_t)l * ND, N);
  }
}

// Round 3
// 1446.035 us; speedup vs baseline: 1.1697x; 1.0226x over previous
//
#include <hip/hip_runtime.h>
#include <math.h>

#define DD 64
#define CHUNK 1024

static inline int divup(int a, int b){ return (a + b - 1) / b; }

// --- histogram of row (for degree) and col (for CSR) ---
__global__ void hist_k(const int* __restrict__ edg, int* __restrict__ rowcnt,
                       int* __restrict__ colcnt, int E){
  int e = blockIdx.x * 256 + threadIdx.x;
  if (e < E){
    atomicAdd(&rowcnt[edg[e]], 1);      // edgidx[0] = rows
    atomicAdd(&colcnt[edg[E + e]], 1);  // edgidx[1] = cols
  }
}

// dinv = (rowcnt + 2)^-1/2   (improved=True self loops, weight 2)
__global__ void dinv_k(const int* __restrict__ rowcnt, float* __restrict__ dinv, int N){
  int i = blockIdx.x * 256 + threadIdx.x;
  if (i < N) dinv[i] = 1.0f / sqrtf((float)rowcnt[i] + 2.0f);
}

// --- 3-kernel exclusive scan of colcnt -> offsets (N+1) ---
__global__ void scan1_k(const int* __restrict__ cnt, int* __restrict__ bsum, int N){
  __shared__ int sh[256];
  int t = threadIdx.x;
  int base = blockIdx.x * CHUNK + t * 4;
  int s = 0;
  #pragma unroll
  for (int j = 0; j < 4; j++){ int g = base + j; if (g < N) s += cnt[g]; }
  sh[t] = s; __syncthreads();
  for (int off = 128; off > 0; off >>= 1){
    if (t < off) sh[t] += sh[t + off];
    __syncthreads();
  }
  if (t == 0) bsum[blockIdx.x] = sh[0];
}

__global__ void scan2_k(const int* __restrict__ bsum, int* __restrict__ bpre, int NB){
  __shared__ int sh[128];
  int t = threadIdx.x;
  int v = (t < NB) ? bsum[t] : 0;
  sh[t] = v; __syncthreads();
  for (int off = 1; off < 128; off <<= 1){
    int x = (t >= off) ? sh[t - off] : 0;
    __syncthreads();
    sh[t] += x;
    __syncthreads();
  }
  if (t < NB) bpre[t] = sh[t] - v;   // exclusive
}

__global__ void scan3_k(const int* __restrict__ cnt, const int* __restrict__ bpre,
                        int* __restrict__ offsets, int N){
  __shared__ int sh[256];
  int t = threadIdx.x, b = blockIdx.x;
  int base = b * CHUNK + t * 4;
  int v[4]; int s = 0;
  #pragma unroll
  for (int j = 0; j < 4; j++){ int g = base + j; v[j] = (g < N) ? cnt[g] : 0; s += v[j]; }
  sh[t] = s; __syncthreads();
  for (int off = 1; off < 256; off <<= 1){
    int x = (t >= off) ? sh[t - off] : 0;
    __syncthreads();
    sh[t] += x;
    __syncthreads();
  }
  int run = sh[t] - s + bpre[b];   // exclusive prefix at base
  #pragma unroll
  for (int j = 0; j < 4; j++){
    int g = base + j;
    if (g <= N) offsets[g] = run;
    run += v[j];
  }
}

// --- scatter edges into CSR (by col), weight = dinv[row]*dinv[col] ---
__global__ void scatter_k(const int* __restrict__ edg, const float* __restrict__ dinv,
                          const int* __restrict__ offsets, int* __restrict__ cursor,
                          int* __restrict__ csr_src, float* __restrict__ csr_w, int E){
  int e = blockIdx.x * 256 + threadIdx.x;
  if (e < E){
    int r = edg[e];
    int c = edg[E + e];
    int pos = offsets[c] + atomicAdd(&cursor[c], 1);
    csr_src[pos] = r;
    csr_w[pos] = dinv[r] * dinv[c];
  }
}

// --- fused aggregation of two feature matrices: one wave per node, lane = feature ---
__global__ void agg2_k(const float* __restrict__ X, const float* __restrict__ H,
                       const int* __restrict__ offsets, const int* __restrict__ src,
                       const float* __restrict__ w, const float* __restrict__ dinv,
                       float* __restrict__ AX, float* __restrict__ AH, int N){
  int wid = (blockIdx.x * blockDim.x + threadIdx.x) >> 6;
  int lane = threadIdx.x & 63;
  if (wid >= N) return;
  float dv = dinv[wid];
  float selfw = 2.0f * dv * dv;
  size_t me = (size_t)wid * DD + lane;
  float ax = selfw * X[me];
  float ah = selfw * H[me];
  float ax2 = 0.0f, ah2 = 0.0f;
  int s0 = offsets[wid], s1 = offsets[wid + 1];
  int e = s0;
  for (; e + 2 <= s1; e += 2){
    int sa = src[e], sb = src[e + 1];
    float wa = w[e], wb = w[e + 1];
    size_t oa = (size_t)sa * DD + lane;
    size_t ob = (size_t)sb * DD + lane;
    ax  += wa * X[oa];
    ah  += wa * H[oa];
    ax2 += wb * X[ob];
    ah2 += wb * H[ob];
  }
  if (e < s1){
    int sa = src[e];
    float wa = w[e];
    size_t oa = (size_t)sa * DD + lane;
    ax += wa * X[oa];
    ah += wa * H[oa];
  }
  AX[me] = ax + ax2;
  AH[me] = ah + ah2;
}

__global__ void agg1_k(const float* __restrict__ X,
                       const int* __restrict__ offsets, const int* __restrict__ src,
                       const float* __restrict__ w, const float* __restrict__ dinv,
                       float* __restrict__ AX, int N){
  int wid = (blockIdx.x * blockDim.x + threadIdx.x) >> 6;
  int lane = threadIdx.x & 63;
  if (wid >= N) return;
  float dv = dinv[wid];
  float selfw = 2.0f * dv * dv;
  size_t me = (size_t)wid * DD + lane;
  float ax = selfw * X[me];
  float ax2 = 0.0f;
  int s0 = offsets[wid], s1 = offsets[wid + 1];
  int e = s0;
  for (; e + 2 <= s1; e += 2){
    int sa = src[e], sb = src[e + 1];
    float wa = w[e], wb = w[e + 1];
    ax  += wa * X[(size_t)sa * DD + lane];
    ax2 += wb * X[(size_t)sb * DD + lane];
  }
  if (e < s1){
    ax += w[e] * X[(size_t)src[e] * DD + lane];
  }
  AX[me] = ax + ax2;
}

// ---------------------------------------------------------------------------
// Dense gate kernel v3: thread = (node, j-half), half wave-uniform via
// readfirstlane so W/bias addresses stay scalar (s_load).  Each thread
// streams its AX/AH rows ONCE and feeds all three gate accumulators
// (z, r, t1) simultaneously -> row re-traversals drop 10x -> 2x, and the
// grid doubles (782 blocks) for better CU coverage.
// ---------------------------------------------------------------------------
__global__ __launch_bounds__(256) void gate3_k(
    const float* __restrict__ AX, const float* __restrict__ AH,
    const float* __restrict__ Hh,
    const float* __restrict__ Wxz, const float* __restrict__ Whz,
    const float* __restrict__ Wxr, const float* __restrict__ Whr,
    const float* __restrict__ Wxh,
    const float* __restrict__ bxz, const float* __restrict__ bhz,
    const float* __restrict__ bxr, const float* __restrict__ bhr,
    const float* __restrict__ bxh, const float* __restrict__ bhh,
    float* __restrict__ zb, float* __restrict__ rhb,
    float* __restrict__ t1b, int N)
{
  const int lane = threadIdx.x & 63;
  const int wv   = threadIdx.x >> 6;                            // 0..3
  const int half = __builtin_amdgcn_readfirstlane(wv & 1);      // wave-uniform
  const int ng   = __builtin_amdgcn_readfirstlane(wv >> 1);     // 0..1
  const int node = blockIdx.x * 128 + ng * 64 + lane;
  const int nc   = node < N ? node : N - 1;
  const bool wr  = node < N;
  const int jb   = half * 32;

  const float4* axr = (const float4*)(AX + (size_t)nc * DD);
  const float4* ahr = (const float4*)(AH + (size_t)nc * DD);

  float accz[32], accr[32], acct[32];
  #pragma unroll
  for (int j = 0; j < 32; j++){
    accz[j] = bxz[jb + j] + bhz[jb + j];
    accr[j] = bxr[jb + j] + bhr[jb + j];
    acct[j] = bxh[jb + j] + bhh[jb + j];
  }

  #pragma unroll 2
  for (int k4 = 0; k4 < 16; k4++){
    float4 a4 = axr[k4];
    float4 h4 = ahr[k4];
    #pragma unroll
    for (int kk = 0; kk < 4; kk++){
      const float xk = kk == 0 ? a4.x : kk == 1 ? a4.y : kk == 2 ? a4.z : a4.w;
      const float hk = kk == 0 ? h4.x : kk == 1 ? h4.y : kk == 2 ? h4.z : h4.w;
      const int k = k4 * 4 + kk;
      const float* wxz = Wxz + k * DD + jb;
      const float* whz = Whz + k * DD + jb;
      const float* wxr = Wxr + k * DD + jb;
      const float* whr = Whr + k * DD + jb;
      const float* wxh = Wxh + k * DD + jb;
      #pragma unroll
      for (int j = 0; j < 32; j++){
        accz[j] += xk * wxz[j] + hk * whz[j];
        accr[j] += xk * wxr[j] + hk * whr[j];
        acct[j] += xk * wxh[j];
      }
    }
  }

  if (wr){
    const float4* hr = (const float4*)(Hh + (size_t)node * DD + jb);
    float4* zrow = (float4*)(zb  + (size_t)node * DD + jb);
    float4* rrow = (float4*)(rhb + (size_t)node * DD + jb);
    float4* trow = (float4*)(t1b + (size_t)node * DD + jb);
    #pragma unroll
    for (int q = 0; q < 8; q++){
      float4 hv = hr[q];
      float4 vz, vr, vt;
      vz.x = 1.0f / (1.0f + __expf(-accz[4 * q + 0]));
      vz.y = 1.0f / (1.0f + __expf(-accz[4 * q + 1]));
      vz.z = 1.0f / (1.0f + __expf(-accz[4 * q + 2]));
      vz.w = 1.0f / (1.0f + __expf(-accz[4 * q + 3]));
      vr.x = hv.x / (1.0f + __expf(-accr[4 * q + 0]));
      vr.y = hv.y / (1.0f + __expf(-accr[4 * q + 1]));
      vr.z = hv.z / (1.0f + __expf(-accr[4 * q + 2]));
      vr.w = hv.w / (1.0f + __expf(-accr[4 * q + 3]));
      vt.x = acct[4 * q + 0]; vt.y = acct[4 * q + 1];
      vt.z = acct[4 * q + 2]; vt.w = acct[4 * q + 3];
      zrow[q] = vz; rrow[q] = vr; trow[q] = vt;
    }
  }
}

// --- output v3: same (node, half) mapping.  h_t = tanh(t1 + Arh@Whh),
//     ho = z*h + (1-z)*h_t, written to both output copies. ---
__global__ __launch_bounds__(256) void out3_k(
    const float* __restrict__ Arh, const float* __restrict__ t1b,
    const float* __restrict__ zb, const float* __restrict__ Hh,
    const float* __restrict__ Whh,
    float* __restrict__ o1, float* __restrict__ o2, int N)
{
  const int lane = threadIdx.x & 63;
  const int wv   = threadIdx.x >> 6;
  const int half = __builtin_amdgcn_readfirstlane(wv & 1);
  const int ng   = __builtin_amdgcn_readfirstlane(wv >> 1);
  const int node = blockIdx.x * 128 + ng * 64 + lane;
  const int nc   = node < N ? node : N - 1;
  const bool wr  = node < N;
  const int jb   = half * 32;

  const float4* arr = (const float4*)(Arh + (size_t)nc * DD);
  const float4* tr  = (const float4*)(t1b + (size_t)nc * DD + jb);

  float acc[32];
  #pragma unroll
  for (int q = 0; q < 8; q++){
    float4 t4 = tr[q];
    acc[4 * q + 0] = t4.x; acc[4 * q + 1] = t4.y;
    acc[4 * q + 2] = t4.z; acc[4 * q + 3] = t4.w;
  }

  #pragma unroll 2
  for (int k4 = 0; k4 < 16; k4++){
    float4 a4 = arr[k4];
    #pragma unroll
    for (int kk = 0; kk < 4; kk++){
      const float xk = kk == 0 ? a4.x : kk == 1 ? a4.y : kk == 2 ? a4.z : a4.w;
      const float* wx = Whh + (k4 * 4 + kk) * DD + jb;
      #pragma unroll
      for (int j = 0; j < 32; j++) acc[j] += xk * wx[j];
    }
  }

  if (wr){
    const float4* zr = (const float4*)(zb + (size_t)node * DD + jb);
    const float4* hr = (const float4*)(Hh + (size_t)node * DD + jb);
    float4* o1row = (float4*)(o1 + (size_t)node * DD + jb);
    float4* o2row = (float4*)(o2 + (size_t)node * DD + jb);
    #pragma unroll
    for (int q = 0; q < 8; q++){
      float4 z4 = zr[q];
      float4 h4 = hr[q];
      float4 v;
      float ht0 = tanhf(acc[4 * q + 0]);
      float ht1 = tanhf(acc[4 * q + 1]);
      float ht2 = tanhf(acc[4 * q + 2]);
      float ht3 = tanhf(acc[4 * q + 3]);
      v.x = z4.x * h4.x + (1.0f - z4.x) * ht0;
      v.y = z4.y * h4.y + (1.0f - z4.y) * ht1;
      v.z = z4.z * h4.z + (1.0f - z4.z) * ht2;
      v.w = z4.w * h4.w + (1.0f - z4.w) * ht3;
      o1row[q] = v;
      o2row[q] = v;
    }
  }
}

extern "C" void kernel_launch(void* const* d_in, const int* in_sizes, int n_in,
                              void* d_out, int out_size, void* d_ws, size_t ws_size,
                              hipStream_t stream){
  const float* inp = (const float*)d_in[0];
  const float* h   = (const float*)d_in[1];
  const int*   edg = (const int*)d_in[2];
  const float* Wxz = (const float*)d_in[3];
  const float* Whz = (const float*)d_in[4];
  const float* Wxr = (const float*)d_in[5];
  const float* Whr = (const float*)d_in[6];
  const float* Wxh = (const float*)d_in[7];
  const float* Whh = (const float*)d_in[8];
  const float* bxz = (const float*)d_in[9];
  const float* bhz = (const float*)d_in[10];
  const float* bxr = (const float*)d_in[11];
  const float* bhr = (const float*)d_in[12];
  const float* bxh = (const float*)d_in[13];
  const float* bhh = (const float*)d_in[14];
  float* out = (float*)d_out;

  const int ND = in_sizes[0];
  const int N  = ND / DD;
  const int E  = in_sizes[2] / 2;
  const int L  = in_sizes[1] / ND;

  // workspace carve (all 256B-aligned)
  char* p = (char*)d_ws;
  auto alloc = [&](size_t bytes) -> void* {
    void* r = (void*)p;
    p += ((bytes + 255) / 256) * 256;
    return r;
  };
  int*   rowcnt  = (int*)alloc((size_t)3 * N * 4);  // rowcnt | colcnt | cursor contiguous
  int*   colcnt  = rowcnt + N;
  int*   cursor  = colcnt + N;
  int*   offsets = (int*)alloc((size_t)(N + 1) * 4);
  int*   bsum    = (int*)alloc(128 * 4);
  int*   bpre    = (int*)alloc(128 * 4);
  float* dinv    = (float*)alloc((size_t)N * 4);
  int*   csr_src = (int*)alloc((size_t)E * 4);
  float* csr_w   = (float*)alloc((size_t)E * 4);
  float* Ax      = (float*)alloc((size_t)ND * 4);
  float* Ah      = (float*)alloc((size_t)ND * 4);
  float* Arh     = (float*)alloc((size_t)ND * 4);
  float* zb      = (float*)alloc((size_t)ND * 4);
  float* rhb     = (float*)alloc((size_t)ND * 4);
  float* t1b     = (float*)alloc((size_t)ND * 4);

  hipMemsetAsync(rowcnt, 0, (size_t)3 * N * 4, stream);

  const int NB = divup(N, CHUNK);
  hist_k<<<divup(E, 256), 256, 0, stream>>>(edg, rowcnt, colcnt, E);
  dinv_k<<<divup(N, 256), 256, 0, stream>>>(rowcnt, dinv, N);
  scan1_k<<<NB, 256, 0, stream>>>(colcnt, bsum, N);
  scan2_k<<<1, 128, 0, stream>>>(bsum, bpre, NB);
  scan3_k<<<NB, 256, 0, stream>>>(colcnt, bpre, offsets, N);
  scatter_k<<<divup(E, 256), 256, 0, stream>>>(edg, dinv, offsets, cursor, csr_src, csr_w, E);

  const int aggBlocks = divup(N, 4);    // 4 waves (nodes) per 256-thread block
  const int dBlocks   = divup(N, 128);  // (node, half) threads: 128 nodes/block

  for (int l = 0; l < L; l++){
    const float* X  = (l == 0) ? inp : out + (size_t)(l - 1) * ND;
    const float* Hh = h + (size_t)l * ND;
    agg2_k<<<aggBlocks, 256, 0, stream>>>(X, Hh, offsets, csr_src, csr_w, dinv, Ax, Ah, N);
    gate3_k<<<dBlocks, 256, 0, stream>>>(Ax, Ah, Hh,
        Wxz + (size_t)l * DD * DD, Whz + (size_t)l * DD * DD,
        Wxr + (size_t)l * DD * DD, Whr + (size_t)l * DD * DD,
        Wxh + (size_t)l * DD * DD,
        bxz + (size_t)l * DD, bhz + (size_t)l * DD,
        bxr + (size_t)l * DD, bhr + (size_t)l * DD,
        bxh + (size_t)l * DD, bhh + (size_t)l * DD,
        zb, rhb, t1b, N);
    agg1_k<<<aggBlocks, 256, 0, stream>>>(rhb, offsets, csr_src, csr_w, dinv, Arh, N);
    out3_k<<<dBlocks, 256, 0, stream>>>(Arh, t1b, zb, Hh, Whh + (size_t)l * DD * DD,
        out + (size_t)l * ND, out + (size_t)L * ND + (size_t)l * ND, N);
  }
}

// Round 4
// 984.873 us; speedup vs baseline: 1.7174x; 1.4682x over previous
//
#include <hip/hip_runtime.h>
#include <math.h>

#define DD 64
#define CHUNK 1024

static inline int divup(int a, int b){ return (a + b - 1) / b; }

__device__ __forceinline__ float f4e(const float4& v, int kk){
  return kk == 0 ? v.x : kk == 1 ? v.y : kk == 2 ? v.z : v.w;
}

// --- histogram of row (for degree) and col (for CSR) ---
__global__ void hist_k(const int* __restrict__ edg, int* __restrict__ rowcnt,
                       int* __restrict__ colcnt, int E){
  int e = blockIdx.x * 256 + threadIdx.x;
  if (e < E){
    atomicAdd(&rowcnt[edg[e]], 1);      // edgidx[0] = rows
    atomicAdd(&colcnt[edg[E + e]], 1);  // edgidx[1] = cols
  }
}

// dinv = (rowcnt + 2)^-1/2   (improved=True self loops, weight 2)
__global__ void dinv_k(const int* __restrict__ rowcnt, float* __restrict__ dinv, int N){
  int i = blockIdx.x * 256 + threadIdx.x;
  if (i < N) dinv[i] = 1.0f / sqrtf((float)rowcnt[i] + 2.0f);
}

// --- 3-kernel exclusive scan of colcnt -> offsets (N+1) ---
__global__ void scan1_k(const int* __restrict__ cnt, int* __restrict__ bsum, int N){
  __shared__ int sh[256];
  int t = threadIdx.x;
  int base = blockIdx.x * CHUNK + t * 4;
  int s = 0;
  #pragma unroll
  for (int j = 0; j < 4; j++){ int g = base + j; if (g < N) s += cnt[g]; }
  sh[t] = s; __syncthreads();
  for (int off = 128; off > 0; off >>= 1){
    if (t < off) sh[t] += sh[t + off];
    __syncthreads();
  }
  if (t == 0) bsum[blockIdx.x] = sh[0];
}

__global__ void scan2_k(const int* __restrict__ bsum, int* __restrict__ bpre, int NB){
  __shared__ int sh[128];
  int t = threadIdx.x;
  int v = (t < NB) ? bsum[t] : 0;
  sh[t] = v; __syncthreads();
  for (int off = 1; off < 128; off <<= 1){
    int x = (t >= off) ? sh[t - off] : 0;
    __syncthreads();
    sh[t] += x;
    __syncthreads();
  }
  if (t < NB) bpre[t] = sh[t] - v;   // exclusive
}

__global__ void scan3_k(const int* __restrict__ cnt, const int* __restrict__ bpre,
                        int* __restrict__ offsets, int N){
  __shared__ int sh[256];
  int t = threadIdx.x, b = blockIdx.x;
  int base = b * CHUNK + t * 4;
  int v[4]; int s = 0;
  #pragma unroll
  for (int j = 0; j < 4; j++){ int g = base + j; v[j] = (g < N) ? cnt[g] : 0; s += v[j]; }
  sh[t] = s; __syncthreads();
  for (int off = 1; off < 256; off <<= 1){
    int x = (t >= off) ? sh[t - off] : 0;
    __syncthreads();
    sh[t] += x;
    __syncthreads();
  }
  int run = sh[t] - s + bpre[b];   // exclusive prefix at base
  #pragma unroll
  for (int j = 0; j < 4; j++){
    int g = base + j;
    if (g <= N) offsets[g] = run;
    run += v[j];
  }
}

// --- scatter edges into CSR (by col), weight = dinv[row]*dinv[col] ---
__global__ void scatter_k(const int* __restrict__ edg, const float* __restrict__ dinv,
                          const int* __restrict__ offsets, int* __restrict__ cursor,
                          int* __restrict__ csr_src, float* __restrict__ csr_w, int E){
  int e = blockIdx.x * 256 + threadIdx.x;
  if (e < E){
    int r = edg[e];
    int c = edg[E + e];
    int pos = offsets[c] + atomicAdd(&cursor[c], 1);
    csr_src[pos] = r;
    csr_w[pos] = dinv[r] * dinv[c];
  }
}

// --- fused aggregation of two feature matrices: one wave per node, lane = feature ---
__global__ void agg2_k(const float* __restrict__ X, const float* __restrict__ H,
                       const int* __restrict__ offsets, const int* __restrict__ src,
                       const float* __restrict__ w, const float* __restrict__ dinv,
                       float* __restrict__ AX, float* __restrict__ AH, int N){
  int wid = (blockIdx.x * blockDim.x + threadIdx.x) >> 6;
  int lane = threadIdx.x & 63;
  if (wid >= N) return;
  float dv = dinv[wid];
  float selfw = 2.0f * dv * dv;
  size_t me = (size_t)wid * DD + lane;
  float ax = selfw * X[me];
  float ah = selfw * H[me];
  float ax2 = 0.0f, ah2 = 0.0f;
  int s0 = offsets[wid], s1 = offsets[wid + 1];
  int e = s0;
  for (; e + 2 <= s1; e += 2){
    int sa = src[e], sb = src[e + 1];
    float wa = w[e], wb = w[e + 1];
    size_t oa = (size_t)sa * DD + lane;
    size_t ob = (size_t)sb * DD + lane;
    ax  += wa * X[oa];
    ah  += wa * H[oa];
    ax2 += wb * X[ob];
    ah2 += wb * H[ob];
  }
  if (e < s1){
    int sa = src[e];
    float wa = w[e];
    size_t oa = (size_t)sa * DD + lane;
    ax += wa * X[oa];
    ah += wa * H[oa];
  }
  AX[me] = ax + ax2;
  AH[me] = ah + ah2;
}

__global__ void agg1_k(const float* __restrict__ X,
                       const int* __restrict__ offsets, const int* __restrict__ src,
                       const float* __restrict__ w, const float* __restrict__ dinv,
                       float* __restrict__ AX, int N){
  int wid = (blockIdx.x * blockDim.x + threadIdx.x) >> 6;
  int lane = threadIdx.x & 63;
  if (wid >= N) return;
  float dv = dinv[wid];
  float selfw = 2.0f * dv * dv;
  size_t me = (size_t)wid * DD + lane;
  float ax = selfw * X[me];
  float ax2 = 0.0f;
  int s0 = offsets[wid], s1 = offsets[wid + 1];
  int e = s0;
  for (; e + 2 <= s1; e += 2){
    int sa = src[e], sb = src[e + 1];
    float wa = w[e], wb = w[e + 1];
    ax  += wa * X[(size_t)sa * DD + lane];
    ax2 += wb * X[(size_t)sb * DD + lane];
  }
  if (e < s1){
    ax += w[e] * X[(size_t)src[e] * DD + lane];
  }
  AX[me] = ax + ax2;
}

// ---------------------------------------------------------------------------
// Dense gate kernel v4: lane = output feature j (64), wave = 8 nodes.
//  - weight reads W[k][lane]: coalesced 256B vector loads, L1-resident
//  - activation reads AX[node][k4]: wave-uniform float4 broadcast (1 txn),
//    amortized over 5 FMA x 8 nodes
//  - stores zb[node*64+lane]: perfectly coalesced -> kills the 3.5x write
//    amplification of the lane=node layout (WRITE_SIZE 270MB -> ~77MB)
// ---------------------------------------------------------------------------
__global__ __launch_bounds__(256) void gate4_k(
    const float* __restrict__ AX, const float* __restrict__ AH,
    const float* __restrict__ Hh,
    const float* __restrict__ Wxz, const float* __restrict__ Whz,
    const float* __restrict__ Wxr, const float* __restrict__ Whr,
    const float* __restrict__ Wxh,
    const float* __restrict__ bxz, const float* __restrict__ bhz,
    const float* __restrict__ bxr, const float* __restrict__ bhr,
    const float* __restrict__ bxh, const float* __restrict__ bhh,
    float* __restrict__ zb, float* __restrict__ rhb,
    float* __restrict__ t1b, int N)
{
  const int lane = threadIdx.x & 63;
  const int wv   = __builtin_amdgcn_readfirstlane(threadIdx.x >> 6);
  const int nodeBase = blockIdx.x * 32 + wv * 8;
  if (nodeBase >= N) return;

  int nidx[8];
  #pragma unroll
  for (int m = 0; m < 8; m++) nidx[m] = (nodeBase + m < N) ? nodeBase + m : N - 1;

  const float bz = bxz[lane] + bhz[lane];
  const float br = bxr[lane] + bhr[lane];
  const float bt = bxh[lane] + bhh[lane];
  float accz[8], accr[8], acct[8];
  #pragma unroll
  for (int m = 0; m < 8; m++){ accz[m] = bz; accr[m] = br; acct[m] = bt; }

  #pragma unroll 1
  for (int k4 = 0; k4 < 16; k4++){
    float4 a4[8], h4[8];
    #pragma unroll
    for (int m = 0; m < 8; m++){
      a4[m] = ((const float4*)(AX + (size_t)nidx[m] * DD))[k4];
      h4[m] = ((const float4*)(AH + (size_t)nidx[m] * DD))[k4];
    }
    float wxzv[4], whzv[4], wxrv[4], whrv[4], wxhv[4];
    #pragma unroll
    for (int kk = 0; kk < 4; kk++){
      const int k = k4 * 4 + kk;
      wxzv[kk] = Wxz[k * DD + lane];
      whzv[kk] = Whz[k * DD + lane];
      wxrv[kk] = Wxr[k * DD + lane];
      whrv[kk] = Whr[k * DD + lane];
      wxhv[kk] = Wxh[k * DD + lane];
    }
    #pragma unroll
    for (int kk = 0; kk < 4; kk++){
      #pragma unroll
      for (int m = 0; m < 8; m++){
        const float av = f4e(a4[m], kk);
        const float hv = f4e(h4[m], kk);
        accz[m] = fmaf(av, wxzv[kk], fmaf(hv, whzv[kk], accz[m]));
        accr[m] = fmaf(av, wxrv[kk], fmaf(hv, whrv[kk], accr[m]));
        acct[m] = fmaf(av, wxhv[kk], acct[m]);
      }
    }
  }

  #pragma unroll
  for (int m = 0; m < 8; m++){
    const int node = nodeBase + m;
    if (node < N){
      const size_t o = (size_t)node * DD + lane;
      const float hv = Hh[o];
      zb[o]  = 1.0f / (1.0f + __expf(-accz[m]));
      rhb[o] = hv / (1.0f + __expf(-accr[m]));
      t1b[o] = acct[m];
    }
  }
}

// --- output v4: same mapping. h_t = tanh(t1 + Arh@Whh), ho = z*h + (1-z)*h_t ---
__global__ __launch_bounds__(256) void out4_k(
    const float* __restrict__ Arh, const float* __restrict__ t1b,
    const float* __restrict__ zb, const float* __restrict__ Hh,
    const float* __restrict__ Whh,
    float* __restrict__ o1, float* __restrict__ o2, int N)
{
  const int lane = threadIdx.x & 63;
  const int wv   = __builtin_amdgcn_readfirstlane(threadIdx.x >> 6);
  const int nodeBase = blockIdx.x * 32 + wv * 8;
  if (nodeBase >= N) return;

  int nidx[8];
  #pragma unroll
  for (int m = 0; m < 8; m++) nidx[m] = (nodeBase + m < N) ? nodeBase + m : N - 1;

  float acc[8];
  #pragma unroll
  for (int m = 0; m < 8; m++) acc[m] = t1b[(size_t)nidx[m] * DD + lane];

  #pragma unroll 1
  for (int k4 = 0; k4 < 16; k4++){
    float4 a4[8];
    #pragma unroll
    for (int m = 0; m < 8; m++)
      a4[m] = ((const float4*)(Arh + (size_t)nidx[m] * DD))[k4];
    float wh[4];
    #pragma unroll
    for (int kk = 0; kk < 4; kk++)
      wh[kk] = Whh[(k4 * 4 + kk) * DD + lane];
    #pragma unroll
    for (int kk = 0; kk < 4; kk++){
      #pragma unroll
      for (int m = 0; m < 8; m++)
        acc[m] = fmaf(f4e(a4[m], kk), wh[kk], acc[m]);
    }
  }

  #pragma unroll
  for (int m = 0; m < 8; m++){
    const int node = nodeBase + m;
    if (node < N){
      const size_t o = (size_t)node * DD + lane;
      // tanh(x) = 1 - 2/(exp(2x)+1)  (saturates correctly at +-inf)
      const float e = __expf(2.0f * acc[m]);
      const float ht = 1.0f - 2.0f / (e + 1.0f);
      const float z = zb[o];
      const float hv = Hh[o];
      const float ho = z * hv + (1.0f - z) * ht;
      o1[o] = ho;
      o2[o] = ho;
    }
  }
}

extern "C" void kernel_launch(void* const* d_in, const int* in_sizes, int n_in,
                              void* d_out, int out_size, void* d_ws, size_t ws_size,
                              hipStream_t stream){
  const float* inp = (const float*)d_in[0];
  const float* h   = (const float*)d_in[1];
  const int*   edg = (const int*)d_in[2];
  const float* Wxz = (const float*)d_in[3];
  const float* Whz = (const float*)d_in[4];
  const float* Wxr = (const float*)d_in[5];
  const float* Whr = (const float*)d_in[6];
  const float* Wxh = (const float*)d_in[7];
  const float* Whh = (const float*)d_in[8];
  const float* bxz = (const float*)d_in[9];
  const float* bhz = (const float*)d_in[10];
  const float* bxr = (const float*)d_in[11];
  const float* bhr = (const float*)d_in[12];
  const float* bxh = (const float*)d_in[13];
  const float* bhh = (const float*)d_in[14];
  float* out = (float*)d_out;

  const int ND = in_sizes[0];
  const int N  = ND / DD;
  const int E  = in_sizes[2] / 2;
  const int L  = in_sizes[1] / ND;

  // workspace carve (all 256B-aligned)
  char* p = (char*)d_ws;
  auto alloc = [&](size_t bytes) -> void* {
    void* r = (void*)p;
    p += ((bytes + 255) / 256) * 256;
    return r;
  };
  int*   rowcnt  = (int*)alloc((size_t)3 * N * 4);  // rowcnt | colcnt | cursor contiguous
  int*   colcnt  = rowcnt + N;
  int*   cursor  = colcnt + N;
  int*   offsets = (int*)alloc((size_t)(N + 1) * 4);
  int*   bsum    = (int*)alloc(128 * 4);
  int*   bpre    = (int*)alloc(128 * 4);
  float* dinv    = (float*)alloc((size_t)N * 4);
  int*   csr_src = (int*)alloc((size_t)E * 4);
  float* csr_w   = (float*)alloc((size_t)E * 4);
  float* Ax      = (float*)alloc((size_t)ND * 4);
  float* Ah      = (float*)alloc((size_t)ND * 4);
  float* Arh     = (float*)alloc((size_t)ND * 4);
  float* zb      = (float*)alloc((size_t)ND * 4);
  float* rhb     = (float*)alloc((size_t)ND * 4);
  float* t1b     = (float*)alloc((size_t)ND * 4);

  hipMemsetAsync(rowcnt, 0, (size_t)3 * N * 4, stream);

  const int NB = divup(N, CHUNK);
  hist_k<<<divup(E, 256), 256, 0, stream>>>(edg, rowcnt, colcnt, E);
  dinv_k<<<divup(N, 256), 256, 0, stream>>>(rowcnt, dinv, N);
  scan1_k<<<NB, 256, 0, stream>>>(colcnt, bsum, N);
  scan2_k<<<1, 128, 0, stream>>>(bsum, bpre, NB);
  scan3_k<<<NB, 256, 0, stream>>>(colcnt, bpre, offsets, N);
  scatter_k<<<divup(E, 256), 256, 0, stream>>>(edg, dinv, offsets, cursor, csr_src, csr_w, E);

  const int aggBlocks = divup(N, 4);    // 4 waves (nodes) per 256-thread block
  const int dBlocks   = divup(N, 32);   // 4 waves x 8 nodes per block

  for (int l = 0; l < L; l++){
    const float* X  = (l == 0) ? inp : out + (size_t)(l - 1) * ND;
    const float* Hh = h + (size_t)l * ND;
    agg2_k<<<aggBlocks, 256, 0, stream>>>(X, Hh, offsets, csr_src, csr_w, dinv, Ax, Ah, N);
    gate4_k<<<dBlocks, 256, 0, stream>>>(Ax, Ah, Hh,
        Wxz + (size_t)l * DD * DD, Whz + (size_t)l * DD * DD,
        Wxr + (size_t)l * DD * DD, Whr + (size_t)l * DD * DD,
        Wxh + (size_t)l * DD * DD,
        bxz + (size_t)l * DD, bhz + (size_t)l * DD,
        bxr + (size_t)l * DD, bhr + (size_t)l * DD,
        bxh + (size_t)l * DD, bhh + (size_t)l * DD,
        zb, rhb, t1b, N);
    agg1_k<<<aggBlocks, 256, 0, stream>>>(rhb, offsets, csr_src, csr_w, dinv, Arh, N);
    out4_k<<<dBlocks, 256, 0, stream>>>(Arh, t1b, zb, Hh, Whh + (size_t)l * DD * DD,
        out + (size_t)l * ND, out + (size_t)L * ND + (size_t)l * ND, N);
  }
}

// Round 5
// 970.285 us; speedup vs baseline: 1.7432x; 1.0150x over previous
//
#include <hip/hip_runtime.h>
#include <hip/hip_fp16.h>
#include <math.h>
#include <stdint.h>

#define DD 64
#define CHUNK 1024

static inline int divup(int a, int b){ return (a + b - 1) / b; }

__device__ __forceinline__ float f4e(const float4& v, int kk){
  return kk == 0 ? v.x : kk == 1 ? v.y : kk == 2 ? v.z : v.w;
}

// --- histogram of row (for degree) and col (for CSR) ---
__global__ void hist_k(const int* __restrict__ edg, int* __restrict__ rowcnt,
                       int* __restrict__ colcnt, int E){
  int e = blockIdx.x * 256 + threadIdx.x;
  if (e < E){
    atomicAdd(&rowcnt[edg[e]], 1);      // edgidx[0] = rows
    atomicAdd(&colcnt[edg[E + e]], 1);  // edgidx[1] = cols
  }
}

// dinv = (rowcnt + 2)^-1/2   (improved=True self loops, weight 2)
__global__ void dinv_k(const int* __restrict__ rowcnt, float* __restrict__ dinv, int N){
  int i = blockIdx.x * 256 + threadIdx.x;
  if (i < N) dinv[i] = 1.0f / sqrtf((float)rowcnt[i] + 2.0f);
}

// --- 3-kernel exclusive scan of colcnt -> offsets (N+1) ---
__global__ void scan1_k(const int* __restrict__ cnt, int* __restrict__ bsum, int N){
  __shared__ int sh[256];
  int t = threadIdx.x;
  int base = blockIdx.x * CHUNK + t * 4;
  int s = 0;
  #pragma unroll
  for (int j = 0; j < 4; j++){ int g = base + j; if (g < N) s += cnt[g]; }
  sh[t] = s; __syncthreads();
  for (int off = 128; off > 0; off >>= 1){
    if (t < off) sh[t] += sh[t + off];
    __syncthreads();
  }
  if (t == 0) bsum[blockIdx.x] = sh[0];
}

__global__ void scan2_k(const int* __restrict__ bsum, int* __restrict__ bpre, int NB){
  __shared__ int sh[128];
  int t = threadIdx.x;
  int v = (t < NB) ? bsum[t] : 0;
  sh[t] = v; __syncthreads();
  for (int off = 1; off < 128; off <<= 1){
    int x = (t >= off) ? sh[t - off] : 0;
    __syncthreads();
    sh[t] += x;
    __syncthreads();
  }
  if (t < NB) bpre[t] = sh[t] - v;   // exclusive
}

__global__ void scan3_k(const int* __restrict__ cnt, const int* __restrict__ bpre,
                        int* __restrict__ offsets, int N){
  __shared__ int sh[256];
  int t = threadIdx.x, b = blockIdx.x;
  int base = b * CHUNK + t * 4;
  int v[4]; int s = 0;
  #pragma unroll
  for (int j = 0; j < 4; j++){ int g = base + j; v[j] = (g < N) ? cnt[g] : 0; s += v[j]; }
  sh[t] = s; __syncthreads();
  for (int off = 1; off < 256; off <<= 1){
    int x = (t >= off) ? sh[t - off] : 0;
    __syncthreads();
    sh[t] += x;
    __syncthreads();
  }
  int run = sh[t] - s + bpre[b];   // exclusive prefix at base
  #pragma unroll
  for (int j = 0; j < 4; j++){
    int g = base + j;
    if (g <= N) offsets[g] = run;
    run += v[j];
  }
}

// --- scatter edges into CSR (by col); weights computed on the fly later ---
__global__ void scatter_k(const int* __restrict__ edg,
                          const int* __restrict__ offsets, int* __restrict__ cursor,
                          int* __restrict__ csr_src, int E){
  int e = blockIdx.x * 256 + threadIdx.x;
  if (e < E){
    int r = edg[e];
    int c = edg[E + e];
    int pos = offsets[c] + atomicAdd(&cursor[c], 1);
    csr_src[pos] = r;
  }
}

// --- pack layer-0 gather matrix: XH[node][j] = (half(x), half(h)) ---
__global__ void pack0_k(const float* __restrict__ X, const float* __restrict__ H,
                        __half2* __restrict__ XH, int total){
  int i = blockIdx.x * 256 + threadIdx.x;
  if (i < total){
    __half2 v;
    v.x = __float2half_rn(X[i]);
    v.y = __float2half_rn(H[i]);
    XH[i] = v;
  }
}

// --- fused aggregation of packed (x,h) fp16 rows: one wave per node, lane = feature.
//     256B/edge instead of 512B; weight = dinv[src]*dinv[dst] on the fly (dinv L2-resident).
__global__ void agg2_k(const __half2* __restrict__ XH,
                       const int* __restrict__ offsets, const int* __restrict__ src,
                       const float* __restrict__ dinv,
                       float* __restrict__ AX, float* __restrict__ AH, int N){
  int wid = (blockIdx.x * blockDim.x + threadIdx.x) >> 6;
  int lane = threadIdx.x & 63;
  if (wid >= N) return;
  float dv = dinv[wid];
  float selfw = 2.0f * dv * dv;
  size_t me = (size_t)wid * DD + lane;
  float2 sf = __half22float2(XH[me]);
  float ax = selfw * sf.x;
  float ah = selfw * sf.y;
  float ax2 = 0.0f, ah2 = 0.0f;
  int s0 = offsets[wid], s1 = offsets[wid + 1];
  int e = s0;
  for (; e + 2 <= s1; e += 2){
    int sa = src[e], sb = src[e + 1];
    float wa = dinv[sa] * dv, wb = dinv[sb] * dv;
    float2 fa = __half22float2(XH[(size_t)sa * DD + lane]);
    float2 fb = __half22float2(XH[(size_t)sb * DD + lane]);
    ax  += wa * fa.x;
    ah  += wa * fa.y;
    ax2 += wb * fb.x;
    ah2 += wb * fb.y;
  }
  if (e < s1){
    int sa = src[e];
    float wa = dinv[sa] * dv;
    float2 fa = __half22float2(XH[(size_t)sa * DD + lane]);
    ax += wa * fa.x;
    ah += wa * fa.y;
  }
  AX[me] = ax + ax2;
  AH[me] = ah + ah2;
}

// --- aggregation of fp16 rows (r*h): 128B/edge ---
__global__ void agg1_k(const __half* __restrict__ RH,
                       const int* __restrict__ offsets, const int* __restrict__ src,
                       const float* __restrict__ dinv,
                       float* __restrict__ AX, int N){
  int wid = (blockIdx.x * blockDim.x + threadIdx.x) >> 6;
  int lane = threadIdx.x & 63;
  if (wid >= N) return;
  float dv = dinv[wid];
  float selfw = 2.0f * dv * dv;
  size_t me = (size_t)wid * DD + lane;
  float ax = selfw * __half2float(RH[me]);
  float ax2 = 0.0f;
  int s0 = offsets[wid], s1 = offsets[wid + 1];
  int e = s0;
  for (; e + 2 <= s1; e += 2){
    int sa = src[e], sb = src[e + 1];
    float wa = dinv[sa] * dv, wb = dinv[sb] * dv;
    ax  += wa * __half2float(RH[(size_t)sa * DD + lane]);
    ax2 += wb * __half2float(RH[(size_t)sb * DD + lane]);
  }
  if (e < s1){
    ax += (dinv[src[e]] * dv) * __half2float(RH[(size_t)src[e] * DD + lane]);
  }
  AX[me] = ax + ax2;
}

// ---------------------------------------------------------------------------
// Dense gate kernel v4: lane = output feature j (64), wave = 8 nodes.
// Writes rhb directly as fp16 (gather input for agg1).
// ---------------------------------------------------------------------------
__global__ __launch_bounds__(256) void gate4_k(
    const float* __restrict__ AX, const float* __restrict__ AH,
    const float* __restrict__ Hh,
    const float* __restrict__ Wxz, const float* __restrict__ Whz,
    const float* __restrict__ Wxr, const float* __restrict__ Whr,
    const float* __restrict__ Wxh,
    const float* __restrict__ bxz, const float* __restrict__ bhz,
    const float* __restrict__ bxr, const float* __restrict__ bhr,
    const float* __restrict__ bxh, const float* __restrict__ bhh,
    float* __restrict__ zb, __half* __restrict__ rhb,
    float* __restrict__ t1b, int N)
{
  const int lane = threadIdx.x & 63;
  const int wv   = __builtin_amdgcn_readfirstlane(threadIdx.x >> 6);
  const int nodeBase = blockIdx.x * 32 + wv * 8;
  if (nodeBase >= N) return;

  int nidx[8];
  #pragma unroll
  for (int m = 0; m < 8; m++) nidx[m] = (nodeBase + m < N) ? nodeBase + m : N - 1;

  const float bz = bxz[lane] + bhz[lane];
  const float br = bxr[lane] + bhr[lane];
  const float bt = bxh[lane] + bhh[lane];
  float accz[8], accr[8], acct[8];
  #pragma unroll
  for (int m = 0; m < 8; m++){ accz[m] = bz; accr[m] = br; acct[m] = bt; }

  #pragma unroll 1
  for (int k4 = 0; k4 < 16; k4++){
    float4 a4[8], h4[8];
    #pragma unroll
    for (int m = 0; m < 8; m++){
      a4[m] = ((const float4*)(AX + (size_t)nidx[m] * DD))[k4];
      h4[m] = ((const float4*)(AH + (size_t)nidx[m] * DD))[k4];
    }
    float wxzv[4], whzv[4], wxrv[4], whrv[4], wxhv[4];
    #pragma unroll
    for (int kk = 0; kk < 4; kk++){
      const int k = k4 * 4 + kk;
      wxzv[kk] = Wxz[k * DD + lane];
      whzv[kk] = Whz[k * DD + lane];
      wxrv[kk] = Wxr[k * DD + lane];
      whrv[kk] = Whr[k * DD + lane];
      wxhv[kk] = Wxh[k * DD + lane];
    }
    #pragma unroll
    for (int kk = 0; kk < 4; kk++){
      #pragma unroll
      for (int m = 0; m < 8; m++){
        const float av = f4e(a4[m], kk);
        const float hv = f4e(h4[m], kk);
        accz[m] = fmaf(av, wxzv[kk], fmaf(hv, whzv[kk], accz[m]));
        accr[m] = fmaf(av, wxrv[kk], fmaf(hv, whrv[kk], accr[m]));
        acct[m] = fmaf(av, wxhv[kk], acct[m]);
      }
    }
  }

  #pragma unroll
  for (int m = 0; m < 8; m++){
    const int node = nodeBase + m;
    if (node < N){
      const size_t o = (size_t)node * DD + lane;
      const float hv = Hh[o];
      zb[o]  = 1.0f / (1.0f + __expf(-accz[m]));
      rhb[o] = __float2half_rn(hv / (1.0f + __expf(-accr[m])));
      t1b[o] = acct[m];
    }
  }
}

// --- output v4: h_t = tanh(t1 + Arh@Whh), ho = z*h + (1-z)*h_t.
//     Optionally packs next layer's XH rows: (half(ho), half(hNext)). ---
__global__ __launch_bounds__(256) void out4_k(
    const float* __restrict__ Arh, const float* __restrict__ t1b,
    const float* __restrict__ zb, const float* __restrict__ Hh,
    const float* __restrict__ Whh,
    float* __restrict__ o1, float* __restrict__ o2,
    const float* __restrict__ hNext, __half2* __restrict__ XHnext,
    int doPack, int N)
{
  const int lane = threadIdx.x & 63;
  const int wv   = __builtin_amdgcn_readfirstlane(threadIdx.x >> 6);
  const int nodeBase = blockIdx.x * 32 + wv * 8;
  if (nodeBase >= N) return;

  int nidx[8];
  #pragma unroll
  for (int m = 0; m < 8; m++) nidx[m] = (nodeBase + m < N) ? nodeBase + m : N - 1;

  float acc[8];
  #pragma unroll
  for (int m = 0; m < 8; m++) acc[m] = t1b[(size_t)nidx[m] * DD + lane];

  #pragma unroll 1
  for (int k4 = 0; k4 < 16; k4++){
    float4 a4[8];
    #pragma unroll
    for (int m = 0; m < 8; m++)
      a4[m] = ((const float4*)(Arh + (size_t)nidx[m] * DD))[k4];
    float wh[4];
    #pragma unroll
    for (int kk = 0; kk < 4; kk++)
      wh[kk] = Whh[(k4 * 4 + kk) * DD + lane];
    #pragma unroll
    for (int kk = 0; kk < 4; kk++){
      #pragma unroll
      for (int m = 0; m < 8; m++)
        acc[m] = fmaf(f4e(a4[m], kk), wh[kk], acc[m]);
    }
  }

  #pragma unroll
  for (int m = 0; m < 8; m++){
    const int node = nodeBase + m;
    if (node < N){
      const size_t o = (size_t)node * DD + lane;
      // tanh(x) = 1 - 2/(exp(2x)+1)  (saturates correctly at +-inf)
      const float e = __expf(2.0f * acc[m]);
      const float ht = 1.0f - 2.0f / (e + 1.0f);
      const float z = zb[o];
      const float hv = Hh[o];
      const float ho = z * hv + (1.0f - z) * ht;
      o1[o] = ho;
      o2[o] = ho;
      if (doPack){
        __half2 v;
        v.x = __float2half_rn(ho);
        v.y = __float2half_rn(hNext[o]);
        XHnext[o] = v;
      }
    }
  }
}

extern "C" void kernel_launch(void* const* d_in, const int* in_sizes, int n_in,
                              void* d_out, int out_size, void* d_ws, size_t ws_size,
                              hipStream_t stream){
  const float* inp = (const float*)d_in[0];
  const float* h   = (const float*)d_in[1];
  const int*   edg = (const int*)d_in[2];
  const float* Wxz = (const float*)d_in[3];
  const float* Whz = (const float*)d_in[4];
  const float* Wxr = (const float*)d_in[5];
  const float* Whr = (const float*)d_in[6];
  const float* Wxh = (const float*)d_in[7];
  const float* Whh = (const float*)d_in[8];
  const float* bxz = (const float*)d_in[9];
  const float* bhz = (const float*)d_in[10];
  const float* bxr = (const float*)d_in[11];
  const float* bhr = (const float*)d_in[12];
  const float* bxh = (const float*)d_in[13];
  const float* bhh = (const float*)d_in[14];
  float* out = (float*)d_out;

  const int ND = in_sizes[0];
  const int N  = ND / DD;
  const int E  = in_sizes[2] / 2;
  const int L  = in_sizes[1] / ND;

  // workspace carve (all 256B-aligned)
  char* p = (char*)d_ws;
  auto alloc = [&](size_t bytes) -> void* {
    void* r = (void*)p;
    p += ((bytes + 255) / 256) * 256;
    return r;
  };
  int*     rowcnt  = (int*)alloc((size_t)3 * N * 4);  // rowcnt | colcnt | cursor
  int*     colcnt  = rowcnt + N;
  int*     cursor  = colcnt + N;
  int*     offsets = (int*)alloc((size_t)(N + 1) * 4);
  int*     bsum    = (int*)alloc(128 * 4);
  int*     bpre    = (int*)alloc(128 * 4);
  float*   dinv    = (float*)alloc((size_t)N * 4);
  int*     csr_src = (int*)alloc((size_t)E * 4);
  __half2* XH      = (__half2*)alloc((size_t)ND * 4);   // (x,h) fp16 pairs
  float*   Ax      = (float*)alloc((size_t)ND * 4);     // also reused as Arh
  float*   Ah      = (float*)alloc((size_t)ND * 4);
  float*   zb      = (float*)alloc((size_t)ND * 4);
  float*   t1b     = (float*)alloc((size_t)ND * 4);
  __half*  rhb     = (__half*)alloc((size_t)ND * 2);
  float*   Arh     = Ax;   // Ax dead after gate4_k; agg1 writes Arh there

  hipMemsetAsync(rowcnt, 0, (size_t)3 * N * 4, stream);

  const int NB = divup(N, CHUNK);
  hist_k<<<divup(E, 256), 256, 0, stream>>>(edg, rowcnt, colcnt, E);
  dinv_k<<<divup(N, 256), 256, 0, stream>>>(rowcnt, dinv, N);
  scan1_k<<<NB, 256, 0, stream>>>(colcnt, bsum, N);
  scan2_k<<<1, 128, 0, stream>>>(bsum, bpre, NB);
  scan3_k<<<NB, 256, 0, stream>>>(colcnt, bpre, offsets, N);
  scatter_k<<<divup(E, 256), 256, 0, stream>>>(edg, offsets, cursor, csr_src, E);
  pack0_k<<<divup(ND, 256), 256, 0, stream>>>(inp, h, XH, ND);

  const int aggBlocks = divup(N, 4);    // 4 waves (nodes) per 256-thread block
  const int dBlocks   = divup(N, 32);   // 4 waves x 8 nodes per block

  for (int l = 0; l < L; l++){
    const float* Hh = h + (size_t)l * ND;
    agg2_k<<<aggBlocks, 256, 0, stream>>>(XH, offsets, csr_src, dinv, Ax, Ah, N);
    gate4_k<<<dBlocks, 256, 0, stream>>>(Ax, Ah, Hh,
        Wxz + (size_t)l * DD * DD, Whz + (size_t)l * DD * DD,
        Wxr + (size_t)l * DD * DD, Whr + (size_t)l * DD * DD,
        Wxh + (size_t)l * DD * DD,
        bxz + (size_t)l * DD, bhz + (size_t)l * DD,
        bxr + (size_t)l * DD, bhr + (size_t)l * DD,
        bxh + (size_t)l * DD, bhh + (size_t)l * DD,
        zb, rhb, t1b, N);
    agg1_k<<<aggBlocks, 256, 0, stream>>>(rhb, offsets, csr_src, dinv, Arh, N);
    const int doPack = (l + 1 < L);
    out4_k<<<dBlocks, 256, 0, stream>>>(Arh, t1b, zb, Hh, Whh + (size_t)l * DD * DD,
        out + (size_t)l * ND, out + (size_t)L * ND + (size_t)l * ND,
        h + (size_t)(l + 1 < L ? l + 1 : l) * ND, XH, doPack, N);
  }
}

// Round 6
// 916.618 us; speedup vs baseline: 1.8453x; 1.0585x over previous
//
#include <hip/hip_runtime.h>
#include <hip/hip_fp16.h>
#include <math.h>
#include <stdint.h>

#define DD 64
#define CHUNK 1024

static inline int divup(int a, int b){ return (a + b - 1) / b; }

__device__ __forceinline__ float f4e(const float4& v, int kk){
  return kk == 0 ? v.x : kk == 1 ? v.y : kk == 2 ? v.z : v.w;
}

// --- histogram of row (degree) and col (CSR); col atomic's return value is
//     the edge's rank within its column -> scatter needs no cursor atomics ---
__global__ void hist_k(const int* __restrict__ edg, int* __restrict__ rowcnt,
                       int* __restrict__ colcnt, int* __restrict__ rank, int E){
  int e = blockIdx.x * 256 + threadIdx.x;
  if (e < E){
    atomicAdd(&rowcnt[edg[e]], 1);                  // edgidx[0] = rows
    rank[e] = atomicAdd(&colcnt[edg[E + e]], 1);    // edgidx[1] = cols
  }
}

// --- scan pass 1 (block sums of colcnt) + fused dinv = (rowcnt+2)^-1/2 ---
__global__ void scan1_k(const int* __restrict__ cnt, const int* __restrict__ rowcnt,
                        float* __restrict__ dinv, int* __restrict__ bsum, int N){
  __shared__ int sh[256];
  int t = threadIdx.x;
  int base = blockIdx.x * CHUNK + t * 4;
  int s = 0;
  #pragma unroll
  for (int j = 0; j < 4; j++){
    int g = base + j;
    if (g < N){
      s += cnt[g];
      dinv[g] = 1.0f / sqrtf((float)rowcnt[g] + 2.0f);
    }
  }
  sh[t] = s; __syncthreads();
  for (int off = 128; off > 0; off >>= 1){
    if (t < off) sh[t] += sh[t + off];
    __syncthreads();
  }
  if (t == 0) bsum[blockIdx.x] = sh[0];
}

__global__ void scan2_k(const int* __restrict__ bsum, int* __restrict__ bpre, int NB){
  __shared__ int sh[128];
  int t = threadIdx.x;
  int v = (t < NB) ? bsum[t] : 0;
  sh[t] = v; __syncthreads();
  for (int off = 1; off < 128; off <<= 1){
    int x = (t >= off) ? sh[t - off] : 0;
    __syncthreads();
    sh[t] += x;
    __syncthreads();
  }
  if (t < NB) bpre[t] = sh[t] - v;   // exclusive
}

__global__ void scan3_k(const int* __restrict__ cnt, const int* __restrict__ bpre,
                        int* __restrict__ offsets, int N){
  __shared__ int sh[256];
  int t = threadIdx.x, b = blockIdx.x;
  int base = b * CHUNK + t * 4;
  int v[4]; int s = 0;
  #pragma unroll
  for (int j = 0; j < 4; j++){ int g = base + j; v[j] = (g < N) ? cnt[g] : 0; s += v[j]; }
  sh[t] = s; __syncthreads();
  for (int off = 1; off < 256; off <<= 1){
    int x = (t >= off) ? sh[t - off] : 0;
    __syncthreads();
    sh[t] += x;
    __syncthreads();
  }
  int run = sh[t] - s + bpre[b];   // exclusive prefix at base
  #pragma unroll
  for (int j = 0; j < 4; j++){
    int g = base + j;
    if (g <= N) offsets[g] = run;
    run += v[j];
  }
}

// --- atomic-free scatter: position = offsets[col] + rank (from hist) ---
__global__ void scatter_k(const int* __restrict__ edg, const int* __restrict__ offsets,
                          const int* __restrict__ rank, int* __restrict__ csr_src, int E){
  int e = blockIdx.x * 256 + threadIdx.x;
  if (e < E){
    csr_src[offsets[edg[E + e]] + rank[e]] = edg[e];
  }
}

// --- pack layer-0 gather matrix: XH[node][j] = (half(x), half(h)) ---
__global__ void pack0_k(const float* __restrict__ X, const float* __restrict__ H,
                        __half2* __restrict__ XH, int total){
  int i = blockIdx.x * 256 + threadIdx.x;
  if (i < total){
    __half2 v;
    v.x = __float2half_rn(X[i]);
    v.y = __float2half_rn(H[i]);
    XH[i] = v;
  }
}

// --- fused aggregation of packed (x,h) fp16 rows: one wave per node, lane = feature.
//     256B/edge; weight = dinv[src]*dinv[dst] on the fly (dinv L2-resident).
__global__ void agg2_k(const __half2* __restrict__ XH,
                       const int* __restrict__ offsets, const int* __restrict__ src,
                       const float* __restrict__ dinv,
                       float* __restrict__ AX, float* __restrict__ AH, int N){
  int wid = (blockIdx.x * blockDim.x + threadIdx.x) >> 6;
  int lane = threadIdx.x & 63;
  if (wid >= N) return;
  float dv = dinv[wid];
  float selfw = 2.0f * dv * dv;
  size_t me = (size_t)wid * DD + lane;
  float2 sf = __half22float2(XH[me]);
  float ax = selfw * sf.x;
  float ah = selfw * sf.y;
  float ax2 = 0.0f, ah2 = 0.0f;
  int s0 = offsets[wid], s1 = offsets[wid + 1];
  int e = s0;
  for (; e + 2 <= s1; e += 2){
    int sa = src[e], sb = src[e + 1];
    float wa = dinv[sa] * dv, wb = dinv[sb] * dv;
    float2 fa = __half22float2(XH[(size_t)sa * DD + lane]);
    float2 fb = __half22float2(XH[(size_t)sb * DD + lane]);
    ax  += wa * fa.x;
    ah  += wa * fa.y;
    ax2 += wb * fb.x;
    ah2 += wb * fb.y;
  }
  if (e < s1){
    int sa = src[e];
    float wa = dinv[sa] * dv;
    float2 fa = __half22float2(XH[(size_t)sa * DD + lane]);
    ax += wa * fa.x;
    ah += wa * fa.y;
  }
  AX[me] = ax + ax2;
  AH[me] = ah + ah2;
}

// --- aggregation of fp16 rows (r*h): 128B/edge ---
__global__ void agg1_k(const __half* __restrict__ RH,
                       const int* __restrict__ offsets, const int* __restrict__ src,
                       const float* __restrict__ dinv,
                       float* __restrict__ AX, int N){
  int wid = (blockIdx.x * blockDim.x + threadIdx.x) >> 6;
  int lane = threadIdx.x & 63;
  if (wid >= N) return;
  float dv = dinv[wid];
  float selfw = 2.0f * dv * dv;
  size_t me = (size_t)wid * DD + lane;
  float ax = selfw * __half2float(RH[me]);
  float ax2 = 0.0f;
  int s0 = offsets[wid], s1 = offsets[wid + 1];
  int e = s0;
  for (; e + 2 <= s1; e += 2){
    int sa = src[e], sb = src[e + 1];
    float wa = dinv[sa] * dv, wb = dinv[sb] * dv;
    ax  += wa * __half2float(RH[(size_t)sa * DD + lane]);
    ax2 += wb * __half2float(RH[(size_t)sb * DD + lane]);
  }
  if (e < s1){
    ax += (dinv[src[e]] * dv) * __half2float(RH[(size_t)src[e] * DD + lane]);
  }
  AX[me] = ax + ax2;
}

// ---------------------------------------------------------------------------
// Dense gate kernel v4: lane = output feature j (64), wave = 8 nodes.
// Writes rhb directly as fp16 (gather input for agg1).
// ---------------------------------------------------------------------------
__global__ __launch_bounds__(256) void gate4_k(
    const float* __restrict__ AX, const float* __restrict__ AH,
    const float* __restrict__ Hh,
    const float* __restrict__ Wxz, const float* __restrict__ Whz,
    const float* __restrict__ Wxr, const float* __restrict__ Whr,
    const float* __restrict__ Wxh,
    const float* __restrict__ bxz, const float* __restrict__ bhz,
    const float* __restrict__ bxr, const float* __restrict__ bhr,
    const float* __restrict__ bxh, const float* __restrict__ bhh,
    float* __restrict__ zb, __half* __restrict__ rhb,
    float* __restrict__ t1b, int N)
{
  const int lane = threadIdx.x & 63;
  const int wv   = __builtin_amdgcn_readfirstlane(threadIdx.x >> 6);
  const int nodeBase = blockIdx.x * 32 + wv * 8;
  if (nodeBase >= N) return;

  int nidx[8];
  #pragma unroll
  for (int m = 0; m < 8; m++) nidx[m] = (nodeBase + m < N) ? nodeBase + m : N - 1;

  const float bz = bxz[lane] + bhz[lane];
  const float br = bxr[lane] + bhr[lane];
  const float bt = bxh[lane] + bhh[lane];
  float accz[8], accr[8], acct[8];
  #pragma unroll
  for (int m = 0; m < 8; m++){ accz[m] = bz; accr[m] = br; acct[m] = bt; }

  #pragma unroll 1
  for (int k4 = 0; k4 < 16; k4++){
    float4 a4[8], h4[8];
    #pragma unroll
    for (int m = 0; m < 8; m++){
      a4[m] = ((const float4*)(AX + (size_t)nidx[m] * DD))[k4];
      h4[m] = ((const float4*)(AH + (size_t)nidx[m] * DD))[k4];
    }
    float wxzv[4], whzv[4], wxrv[4], whrv[4], wxhv[4];
    #pragma unroll
    for (int kk = 0; kk < 4; kk++){
      const int k = k4 * 4 + kk;
      wxzv[kk] = Wxz[k * DD + lane];
      whzv[kk] = Whz[k * DD + lane];
      wxrv[kk] = Wxr[k * DD + lane];
      whrv[kk] = Whr[k * DD + lane];
      wxhv[kk] = Wxh[k * DD + lane];
    }
    #pragma unroll
    for (int kk = 0; kk < 4; kk++){
      #pragma unroll
      for (int m = 0; m < 8; m++){
        const float av = f4e(a4[m], kk);
        const float hv = f4e(h4[m], kk);
        accz[m] = fmaf(av, wxzv[kk], fmaf(hv, whzv[kk], accz[m]));
        accr[m] = fmaf(av, wxrv[kk], fmaf(hv, whrv[kk], accr[m]));
        acct[m] = fmaf(av, wxhv[kk], acct[m]);
      }
    }
  }

  #pragma unroll
  for (int m = 0; m < 8; m++){
    const int node = nodeBase + m;
    if (node < N){
      const size_t o = (size_t)node * DD + lane;
      const float hv = Hh[o];
      zb[o]  = 1.0f / (1.0f + __expf(-accz[m]));
      rhb[o] = __float2half_rn(hv / (1.0f + __expf(-accr[m])));
      t1b[o] = acct[m];
    }
  }
}

// --- output v4: h_t = tanh(t1 + Arh@Whh), ho = z*h + (1-z)*h_t.
//     Optionally packs next layer's XH rows: (half(ho), half(hNext)). ---
__global__ __launch_bounds__(256) void out4_k(
    const float* __restrict__ Arh, const float* __restrict__ t1b,
    const float* __restrict__ zb, const float* __restrict__ Hh,
    const float* __restrict__ Whh,
    float* __restrict__ o1, float* __restrict__ o2,
    const float* __restrict__ hNext, __half2* __restrict__ XHnext,
    int doPack, int N)
{
  const int lane = threadIdx.x & 63;
  const int wv   = __builtin_amdgcn_readfirstlane(threadIdx.x >> 6);
  const int nodeBase = blockIdx.x * 32 + wv * 8;
  if (nodeBase >= N) return;

  int nidx[8];
  #pragma unroll
  for (int m = 0; m < 8; m++) nidx[m] = (nodeBase + m < N) ? nodeBase + m : N - 1;

  float acc[8];
  #pragma unroll
  for (int m = 0; m < 8; m++) acc[m] = t1b[(size_t)nidx[m] * DD + lane];

  #pragma unroll 1
  for (int k4 = 0; k4 < 16; k4++){
    float4 a4[8];
    #pragma unroll
    for (int m = 0; m < 8; m++)
      a4[m] = ((const float4*)(Arh + (size_t)nidx[m] * DD))[k4];
    float wh[4];
    #pragma unroll
    for (int kk = 0; kk < 4; kk++)
      wh[kk] = Whh[(k4 * 4 + kk) * DD + lane];
    #pragma unroll
    for (int kk = 0; kk < 4; kk++){
      #pragma unroll
      for (int m = 0; m < 8; m++)
        acc[m] = fmaf(f4e(a4[m], kk), wh[kk], acc[m]);
    }
  }

  #pragma unroll
  for (int m = 0; m < 8; m++){
    const int node = nodeBase + m;
    if (node < N){
      const size_t o = (size_t)node * DD + lane;
      // tanh(x) = 1 - 2/(exp(2x)+1)  (saturates correctly at +-inf)
      const float e = __expf(2.0f * acc[m]);
      const float ht = 1.0f - 2.0f / (e + 1.0f);
      const float z = zb[o];
      const float hv = Hh[o];
      const float ho = z * hv + (1.0f - z) * ht;
      o1[o] = ho;
      o2[o] = ho;
      if (doPack){
        __half2 v;
        v.x = __float2half_rn(ho);
        v.y = __float2half_rn(hNext[o]);
        XHnext[o] = v;
      }
    }
  }
}

extern "C" void kernel_launch(void* const* d_in, const int* in_sizes, int n_in,
                              void* d_out, int out_size, void* d_ws, size_t ws_size,
                              hipStream_t stream){
  const float* inp = (const float*)d_in[0];
  const float* h   = (const float*)d_in[1];
  const int*   edg = (const int*)d_in[2];
  const float* Wxz = (const float*)d_in[3];
  const float* Whz = (const float*)d_in[4];
  const float* Wxr = (const float*)d_in[5];
  const float* Whr = (const float*)d_in[6];
  const float* Wxh = (const float*)d_in[7];
  const float* Whh = (const float*)d_in[8];
  const float* bxz = (const float*)d_in[9];
  const float* bhz = (const float*)d_in[10];
  const float* bxr = (const float*)d_in[11];
  const float* bhr = (const float*)d_in[12];
  const float* bxh = (const float*)d_in[13];
  const float* bhh = (const float*)d_in[14];
  float* out = (float*)d_out;

  const int ND = in_sizes[0];
  const int N  = ND / DD;
  const int E  = in_sizes[2] / 2;
  const int L  = in_sizes[1] / ND;

  // workspace carve (all 256B-aligned)
  char* p = (char*)d_ws;
  auto alloc = [&](size_t bytes) -> void* {
    void* r = (void*)p;
    p += ((bytes + 255) / 256) * 256;
    return r;
  };
  int*     rowcnt  = (int*)alloc((size_t)2 * N * 4);  // rowcnt | colcnt
  int*     colcnt  = rowcnt + N;
  int*     offsets = (int*)alloc((size_t)(N + 1) * 4);
  int*     bsum    = (int*)alloc(128 * 4);
  int*     bpre    = (int*)alloc(128 * 4);
  float*   dinv    = (float*)alloc((size_t)N * 4);
  int*     rank    = (int*)alloc((size_t)E * 4);
  int*     csr_src = (int*)alloc((size_t)E * 4);
  __half2* XH      = (__half2*)alloc((size_t)ND * 4);   // (x,h) fp16 pairs
  float*   Ax      = (float*)alloc((size_t)ND * 4);     // also reused as Arh
  float*   Ah      = (float*)alloc((size_t)ND * 4);
  float*   zb      = (float*)alloc((size_t)ND * 4);
  float*   t1b     = (float*)alloc((size_t)ND * 4);
  __half*  rhb     = (__half*)alloc((size_t)ND * 2);
  float*   Arh     = Ax;   // Ax dead after gate4_k; agg1 writes Arh there

  hipMemsetAsync(rowcnt, 0, (size_t)2 * N * 4, stream);

  const int NB = divup(N, CHUNK);
  hist_k<<<divup(E, 256), 256, 0, stream>>>(edg, rowcnt, colcnt, rank, E);
  scan1_k<<<NB, 256, 0, stream>>>(colcnt, rowcnt, dinv, bsum, N);
  scan2_k<<<1, 128, 0, stream>>>(bsum, bpre, NB);
  scan3_k<<<NB, 256, 0, stream>>>(colcnt, bpre, offsets, N);
  scatter_k<<<divup(E, 256), 256, 0, stream>>>(edg, offsets, rank, csr_src, E);
  pack0_k<<<divup(ND, 256), 256, 0, stream>>>(inp, h, XH, ND);

  const int aggBlocks = divup(N, 4);    // 4 waves (nodes) per 256-thread block
  const int dBlocks   = divup(N, 32);   // 4 waves x 8 nodes per block

  for (int l = 0; l < L; l++){
    const float* Hh = h + (size_t)l * ND;
    agg2_k<<<aggBlocks, 256, 0, stream>>>(XH, offsets, csr_src, dinv, Ax, Ah, N);
    gate4_k<<<dBlocks, 256, 0, stream>>>(Ax, Ah, Hh,
        Wxz + (size_t)l * DD * DD, Whz + (size_t)l * DD * DD,
        Wxr + (size_t)l * DD * DD, Whr + (size_t)l * DD * DD,
        Wxh + (size_t)l * DD * DD,
        bxz + (size_t)l * DD, bhz + (size_t)l * DD,
        bxr + (size_t)l * DD, bhr + (size_t)l * DD,
        bxh + (size_t)l * DD, bhh + (size_t)l * DD,
        zb, rhb, t1b, N);
    agg1_k<<<aggBlocks, 256, 0, stream>>>(rhb, offsets, csr_src, dinv, Arh, N);
    const int doPack = (l + 1 < L);
    out4_k<<<dBlocks, 256, 0, stream>>>(Arh, t1b, zb, Hh, Whh + (size_t)l * DD * DD,
        out + (size_t)l * ND, out + (size_t)L * ND + (size_t)l * ND,
        h + (size_t)(l + 1 < L ? l + 1 : l) * ND, XH, doPack, N);
  }
}

// Round 7
// 821.439 us; speedup vs baseline: 2.0591x; 1.1159x over previous
//
#include <hip/hip_runtime.h>
#include <hip/hip_fp16.h>
#include <math.h>
#include <stdint.h>

#define DD 64
#define CHUNK 1024

static inline int divup(int a, int b){ return (a + b - 1) / b; }

__device__ __forceinline__ float f4e(const float4& v, int kk){
  return kk == 0 ? v.x : kk == 1 ? v.y : kk == 2 ? v.z : v.w;
}

// --- histogram, 4 edges/thread (int4 loads, 4 atomic round-trips in flight).
//     col atomic's return value = edge's rank within its column. ---
__global__ void hist4_k(const int* __restrict__ edg, int* __restrict__ rowcnt,
                        int* __restrict__ colcnt, int* __restrict__ rank, int E4){
  int i = blockIdx.x * 256 + threadIdx.x;
  if (i < E4){
    int4 r4 = ((const int4*)edg)[i];
    int4 c4 = ((const int4*)(edg))[E4 + i];   // cols start at edg+E, E=E4*4
    atomicAdd(&rowcnt[r4.x], 1);
    atomicAdd(&rowcnt[r4.y], 1);
    atomicAdd(&rowcnt[r4.z], 1);
    atomicAdd(&rowcnt[r4.w], 1);
    int4 k4;
    k4.x = atomicAdd(&colcnt[c4.x], 1);
    k4.y = atomicAdd(&colcnt[c4.y], 1);
    k4.z = atomicAdd(&colcnt[c4.z], 1);
    k4.w = atomicAdd(&colcnt[c4.w], 1);
    ((int4*)rank)[i] = k4;
  }
}

// scalar fallback (E not divisible by 4)
__global__ void hist_k(const int* __restrict__ edg, int* __restrict__ rowcnt,
                       int* __restrict__ colcnt, int* __restrict__ rank, int E){
  int e = blockIdx.x * 256 + threadIdx.x;
  if (e < E){
    atomicAdd(&rowcnt[edg[e]], 1);
    rank[e] = atomicAdd(&colcnt[edg[E + e]], 1);
  }
}

// --- scan pass 1 (block sums of colcnt) + fused dinv = (rowcnt+2)^-1/2 ---
__global__ void scan1_k(const int* __restrict__ cnt, const int* __restrict__ rowcnt,
                        float* __restrict__ dinv, int* __restrict__ bsum, int N){
  __shared__ int sh[256];
  int t = threadIdx.x;
  int base = blockIdx.x * CHUNK + t * 4;
  int s = 0;
  #pragma unroll
  for (int j = 0; j < 4; j++){
    int g = base + j;
    if (g < N){
      s += cnt[g];
      dinv[g] = 1.0f / sqrtf((float)rowcnt[g] + 2.0f);
    }
  }
  sh[t] = s; __syncthreads();
  for (int off = 128; off > 0; off >>= 1){
    if (t < off) sh[t] += sh[t + off];
    __syncthreads();
  }
  if (t == 0) bsum[blockIdx.x] = sh[0];
}

__global__ void scan2_k(const int* __restrict__ bsum, int* __restrict__ bpre, int NB){
  __shared__ int sh[128];
  int t = threadIdx.x;
  int v = (t < NB) ? bsum[t] : 0;
  sh[t] = v; __syncthreads();
  for (int off = 1; off < 128; off <<= 1){
    int x = (t >= off) ? sh[t - off] : 0;
    __syncthreads();
    sh[t] += x;
    __syncthreads();
  }
  if (t < NB) bpre[t] = sh[t] - v;   // exclusive
}

__global__ void scan3_k(const int* __restrict__ cnt, const int* __restrict__ bpre,
                        int* __restrict__ offsets, int N){
  __shared__ int sh[256];
  int t = threadIdx.x, b = blockIdx.x;
  int base = b * CHUNK + t * 4;
  int v[4]; int s = 0;
  #pragma unroll
  for (int j = 0; j < 4; j++){ int g = base + j; v[j] = (g < N) ? cnt[g] : 0; s += v[j]; }
  sh[t] = s; __syncthreads();
  for (int off = 1; off < 256; off <<= 1){
    int x = (t >= off) ? sh[t - off] : 0;
    __syncthreads();
    sh[t] += x;
    __syncthreads();
  }
  int run = sh[t] - s + bpre[b];   // exclusive prefix at base
  #pragma unroll
  for (int j = 0; j < 4; j++){
    int g = base + j;
    if (g <= N) offsets[g] = run;
    run += v[j];
  }
}

// --- atomic-free scatter, 4 edges/thread: pos = offsets[col] + rank ---
__global__ void scatter4_k(const int* __restrict__ edg, const int* __restrict__ offsets,
                           const int* __restrict__ rank, int* __restrict__ csr_src, int E4){
  int i = blockIdx.x * 256 + threadIdx.x;
  if (i < E4){
    int4 r4 = ((const int4*)edg)[i];
    int4 c4 = ((const int4*)(edg))[E4 + i];
    int4 k4 = ((const int4*)rank)[i];
    csr_src[offsets[c4.x] + k4.x] = r4.x;
    csr_src[offsets[c4.y] + k4.y] = r4.y;
    csr_src[offsets[c4.z] + k4.z] = r4.z;
    csr_src[offsets[c4.w] + k4.w] = r4.w;
  }
}

__global__ void scatter_k(const int* __restrict__ edg, const int* __restrict__ offsets,
                          const int* __restrict__ rank, int* __restrict__ csr_src, int E){
  int e = blockIdx.x * 256 + threadIdx.x;
  if (e < E){
    csr_src[offsets[edg[E + e]] + rank[e]] = edg[e];
  }
}

// --- pack layer-0 gather matrix: XH[node][j] = (half(x), half(h)) ---
__global__ void pack0_k(const float* __restrict__ X, const float* __restrict__ H,
                        __half2* __restrict__ XH, int total){
  int i = blockIdx.x * 256 + threadIdx.x;
  if (i < total){
    __half2 v;
    v.x = __float2half_rn(X[i]);
    v.y = __float2half_rn(H[i]);
    XH[i] = v;
  }
}

// --- fused aggregation of packed (x,h) fp16 rows: wave per node, lane = feature.
//     unroll 4: four independent {src -> dinv -> row-gather} chains in flight.
__global__ void agg2_k(const __half2* __restrict__ XH,
                       const int* __restrict__ offsets, const int* __restrict__ src,
                       const float* __restrict__ dinv,
                       float* __restrict__ AX, float* __restrict__ AH, int N){
  int wid = (blockIdx.x * blockDim.x + threadIdx.x) >> 6;
  int lane = threadIdx.x & 63;
  if (wid >= N) return;
  float dv = dinv[wid];
  float selfw = 2.0f * dv * dv;
  size_t me = (size_t)wid * DD + lane;
  float2 sf = __half22float2(XH[me]);
  float ax1 = selfw * sf.x, ah1 = selfw * sf.y;
  float ax2 = 0.0f, ah2 = 0.0f;
  float ax3 = 0.0f, ah3 = 0.0f;
  float ax4 = 0.0f, ah4 = 0.0f;
  int s0 = offsets[wid], s1 = offsets[wid + 1];
  int e = s0;
  for (; e + 4 <= s1; e += 4){
    int sa = src[e], sb = src[e + 1], sc = src[e + 2], sd = src[e + 3];
    float wa = dinv[sa] * dv, wb = dinv[sb] * dv;
    float wc = dinv[sc] * dv, wd = dinv[sd] * dv;
    float2 fa = __half22float2(XH[(size_t)sa * DD + lane]);
    float2 fb = __half22float2(XH[(size_t)sb * DD + lane]);
    float2 fc = __half22float2(XH[(size_t)sc * DD + lane]);
    float2 fd = __half22float2(XH[(size_t)sd * DD + lane]);
    ax1 += wa * fa.x;  ah1 += wa * fa.y;
    ax2 += wb * fb.x;  ah2 += wb * fb.y;
    ax3 += wc * fc.x;  ah3 += wc * fc.y;
    ax4 += wd * fd.x;  ah4 += wd * fd.y;
  }
  for (; e < s1; ++e){
    int sa = src[e];
    float wa = dinv[sa] * dv;
    float2 fa = __half22float2(XH[(size_t)sa * DD + lane]);
    ax1 += wa * fa.x;
    ah1 += wa * fa.y;
  }
  AX[me] = (ax1 + ax2) + (ax3 + ax4);
  AH[me] = (ah1 + ah2) + (ah3 + ah4);
}

// --- aggregation of fp16 rows (r*h), unroll 4 ---
__global__ void agg1_k(const __half* __restrict__ RH,
                       const int* __restrict__ offsets, const int* __restrict__ src,
                       const float* __restrict__ dinv,
                       float* __restrict__ AX, int N){
  int wid = (blockIdx.x * blockDim.x + threadIdx.x) >> 6;
  int lane = threadIdx.x & 63;
  if (wid >= N) return;
  float dv = dinv[wid];
  float selfw = 2.0f * dv * dv;
  size_t me = (size_t)wid * DD + lane;
  float ax1 = selfw * __half2float(RH[me]);
  float ax2 = 0.0f, ax3 = 0.0f, ax4 = 0.0f;
  int s0 = offsets[wid], s1 = offsets[wid + 1];
  int e = s0;
  for (; e + 4 <= s1; e += 4){
    int sa = src[e], sb = src[e + 1], sc = src[e + 2], sd = src[e + 3];
    float wa = dinv[sa] * dv, wb = dinv[sb] * dv;
    float wc = dinv[sc] * dv, wd = dinv[sd] * dv;
    ax1 += wa * __half2float(RH[(size_t)sa * DD + lane]);
    ax2 += wb * __half2float(RH[(size_t)sb * DD + lane]);
    ax3 += wc * __half2float(RH[(size_t)sc * DD + lane]);
    ax4 += wd * __half2float(RH[(size_t)sd * DD + lane]);
  }
  for (; e < s1; ++e){
    ax1 += (dinv[src[e]] * dv) * __half2float(RH[(size_t)src[e] * DD + lane]);
  }
  AX[me] = (ax1 + ax2) + (ax3 + ax4);
}

// ---------------------------------------------------------------------------
// Dense gate kernel v4: lane = output feature j (64), wave = 8 nodes.
// Writes rhb directly as fp16 (gather input for agg1).
// ---------------------------------------------------------------------------
__global__ __launch_bounds__(256) void gate4_k(
    const float* __restrict__ AX, const float* __restrict__ AH,
    const float* __restrict__ Hh,
    const float* __restrict__ Wxz, const float* __restrict__ Whz,
    const float* __restrict__ Wxr, const float* __restrict__ Whr,
    const float* __restrict__ Wxh,
    const float* __restrict__ bxz, const float* __restrict__ bhz,
    const float* __restrict__ bxr, const float* __restrict__ bhr,
    const float* __restrict__ bxh, const float* __restrict__ bhh,
    float* __restrict__ zb, __half* __restrict__ rhb,
    float* __restrict__ t1b, int N)
{
  const int lane = threadIdx.x & 63;
  const int wv   = __builtin_amdgcn_readfirstlane(threadIdx.x >> 6);
  const int nodeBase = blockIdx.x * 32 + wv * 8;
  if (nodeBase >= N) return;

  int nidx[8];
  #pragma unroll
  for (int m = 0; m < 8; m++) nidx[m] = (nodeBase + m < N) ? nodeBase + m : N - 1;

  const float bz = bxz[lane] + bhz[lane];
  const float br = bxr[lane] + bhr[lane];
  const float bt = bxh[lane] + bhh[lane];
  float accz[8], accr[8], acct[8];
  #pragma unroll
  for (int m = 0; m < 8; m++){ accz[m] = bz; accr[m] = br; acct[m] = bt; }

  #pragma unroll 1
  for (int k4 = 0; k4 < 16; k4++){
    float4 a4[8], h4[8];
    #pragma unroll
    for (int m = 0; m < 8; m++){
      a4[m] = ((const float4*)(AX + (size_t)nidx[m] * DD))[k4];
      h4[m] = ((const float4*)(AH + (size_t)nidx[m] * DD))[k4];
    }
    float wxzv[4], whzv[4], wxrv[4], whrv[4], wxhv[4];
    #pragma unroll
    for (int kk = 0; kk < 4; kk++){
      const int k = k4 * 4 + kk;
      wxzv[kk] = Wxz[k * DD + lane];
      whzv[kk] = Whz[k * DD + lane];
      wxrv[kk] = Wxr[k * DD + lane];
      whrv[kk] = Whr[k * DD + lane];
      wxhv[kk] = Wxh[k * DD + lane];
    }
    #pragma unroll
    for (int kk = 0; kk < 4; kk++){
      #pragma unroll
      for (int m = 0; m < 8; m++){
        const float av = f4e(a4[m], kk);
        const float hv = f4e(h4[m], kk);
        accz[m] = fmaf(av, wxzv[kk], fmaf(hv, whzv[kk], accz[m]));
        accr[m] = fmaf(av, wxrv[kk], fmaf(hv, whrv[kk], accr[m]));
        acct[m] = fmaf(av, wxhv[kk], acct[m]);
      }
    }
  }

  #pragma unroll
  for (int m = 0; m < 8; m++){
    const int node = nodeBase + m;
    if (node < N){
      const size_t o = (size_t)node * DD + lane;
      const float hv = Hh[o];
      zb[o]  = 1.0f / (1.0f + __expf(-accz[m]));
      rhb[o] = __float2half_rn(hv / (1.0f + __expf(-accr[m])));
      t1b[o] = acct[m];
    }
  }
}

// --- output v4: h_t = tanh(t1 + Arh@Whh), ho = z*h + (1-z)*h_t.
//     Optionally packs next layer's XH rows: (half(ho), half(hNext)). ---
__global__ __launch_bounds__(256) void out4_k(
    const float* __restrict__ Arh, const float* __restrict__ t1b,
    const float* __restrict__ zb, const float* __restrict__ Hh,
    const float* __restrict__ Whh,
    float* __restrict__ o1, float* __restrict__ o2,
    const float* __restrict__ hNext, __half2* __restrict__ XHnext,
    int doPack, int N)
{
  const int lane = threadIdx.x & 63;
  const int wv   = __builtin_amdgcn_readfirstlane(threadIdx.x >> 6);
  const int nodeBase = blockIdx.x * 32 + wv * 8;
  if (nodeBase >= N) return;

  int nidx[8];
  #pragma unroll
  for (int m = 0; m < 8; m++) nidx[m] = (nodeBase + m < N) ? nodeBase + m : N - 1;

  float acc[8];
  #pragma unroll
  for (int m = 0; m < 8; m++) acc[m] = t1b[(size_t)nidx[m] * DD + lane];

  #pragma unroll 1
  for (int k4 = 0; k4 < 16; k4++){
    float4 a4[8];
    #pragma unroll
    for (int m = 0; m < 8; m++)
      a4[m] = ((const float4*)(Arh + (size_t)nidx[m] * DD))[k4];
    float wh[4];
    #pragma unroll
    for (int kk = 0; kk < 4; kk++)
      wh[kk] = Whh[(k4 * 4 + kk) * DD + lane];
    #pragma unroll
    for (int kk = 0; kk < 4; kk++){
      #pragma unroll
      for (int m = 0; m < 8; m++)
        acc[m] = fmaf(f4e(a4[m], kk), wh[kk], acc[m]);
    }
  }

  #pragma unroll
  for (int m = 0; m < 8; m++){
    const int node = nodeBase + m;
    if (node < N){
      const size_t o = (size_t)node * DD + lane;
      // tanh(x) = 1 - 2/(exp(2x)+1)  (saturates correctly at +-inf)
      const float e = __expf(2.0f * acc[m]);
      const float ht = 1.0f - 2.0f / (e + 1.0f);
      const float z = zb[o];
      const float hv = Hh[o];
      const float ho = z * hv + (1.0f - z) * ht;
      o1[o] = ho;
      o2[o] = ho;
      if (doPack){
        __half2 v;
        v.x = __float2half_rn(ho);
        v.y = __float2half_rn(hNext[o]);
        XHnext[o] = v;
      }
    }
  }
}

extern "C" void kernel_launch(void* const* d_in, const int* in_sizes, int n_in,
                              void* d_out, int out_size, void* d_ws, size_t ws_size,
                              hipStream_t stream){
  const float* inp = (const float*)d_in[0];
  const float* h   = (const float*)d_in[1];
  const int*   edg = (const int*)d_in[2];
  const float* Wxz = (const float*)d_in[3];
  const float* Whz = (const float*)d_in[4];
  const float* Wxr = (const float*)d_in[5];
  const float* Whr = (const float*)d_in[6];
  const float* Wxh = (const float*)d_in[7];
  const float* Whh = (const float*)d_in[8];
  const float* bxz = (const float*)d_in[9];
  const float* bhz = (const float*)d_in[10];
  const float* bxr = (const float*)d_in[11];
  const float* bhr = (const float*)d_in[12];
  const float* bxh = (const float*)d_in[13];
  const float* bhh = (const float*)d_in[14];
  float* out = (float*)d_out;

  const int ND = in_sizes[0];
  const int N  = ND / DD;
  const int E  = in_sizes[2] / 2;
  const int L  = in_sizes[1] / ND;

  // workspace carve (all 256B-aligned)
  char* p = (char*)d_ws;
  auto alloc = [&](size_t bytes) -> void* {
    void* r = (void*)p;
    p += ((bytes + 255) / 256) * 256;
    return r;
  };
  int*     rowcnt  = (int*)alloc((size_t)2 * N * 4);  // rowcnt | colcnt
  int*     colcnt  = rowcnt + N;
  int*     offsets = (int*)alloc((size_t)(N + 1) * 4);
  int*     bsum    = (int*)alloc(128 * 4);
  int*     bpre    = (int*)alloc(128 * 4);
  float*   dinv    = (float*)alloc((size_t)N * 4);
  int*     rank    = (int*)alloc((size_t)E * 4);
  int*     csr_src = (int*)alloc((size_t)E * 4);
  __half2* XH      = (__half2*)alloc((size_t)ND * 4);   // (x,h) fp16 pairs
  float*   Ax      = (float*)alloc((size_t)ND * 4);     // also reused as Arh
  float*   Ah      = (float*)alloc((size_t)ND * 4);
  float*   zb      = (float*)alloc((size_t)ND * 4);
  float*   t1b     = (float*)alloc((size_t)ND * 4);
  __half*  rhb     = (__half*)alloc((size_t)ND * 2);
  float*   Arh     = Ax;   // Ax dead after gate4_k; agg1 writes Arh there

  hipMemsetAsync(rowcnt, 0, (size_t)2 * N * 4, stream);

  const int NB = divup(N, CHUNK);
  if ((E & 3) == 0){
    const int E4 = E / 4;
    hist4_k<<<divup(E4, 256), 256, 0, stream>>>(edg, rowcnt, colcnt, rank, E4);
  } else {
    hist_k<<<divup(E, 256), 256, 0, stream>>>(edg, rowcnt, colcnt, rank, E);
  }
  scan1_k<<<NB, 256, 0, stream>>>(colcnt, rowcnt, dinv, bsum, N);
  scan2_k<<<1, 128, 0, stream>>>(bsum, bpre, NB);
  scan3_k<<<NB, 256, 0, stream>>>(colcnt, bpre, offsets, N);
  if ((E & 3) == 0){
    const int E4 = E / 4;
    scatter4_k<<<divup(E4, 256), 256, 0, stream>>>(edg, offsets, rank, csr_src, E4);
  } else {
    scatter_k<<<divup(E, 256), 256, 0, stream>>>(edg, offsets, rank, csr_src, E);
  }
  pack0_k<<<divup(ND, 256), 256, 0, stream>>>(inp, h, XH, ND);

  const int aggBlocks = divup(N, 4);    // 4 waves (nodes) per 256-thread block
  const int dBlocks   = divup(N, 32);   // 4 waves x 8 nodes per block

  for (int l = 0; l < L; l++){
    const float* Hh = h + (size_t)l * ND;
    agg2_k<<<aggBlocks, 256, 0, stream>>>(XH, offsets, csr_src, dinv, Ax, Ah, N);
    gate4_k<<<dBlocks, 256, 0, stream>>>(Ax, Ah, Hh,
        Wxz + (size_t)l * DD * DD, Whz + (size_t)l * DD * DD,
        Wxr + (size_t)l * DD * DD, Whr + (size_t)l * DD * DD,
        Wxh + (size_t)l * DD * DD,
        bxz + (size_t)l * DD, bhz + (size_t)l * DD,
        bxr + (size_t)l * DD, bhr + (size_t)l * DD,
        bxh + (size_t)l * DD, bhh + (size_t)l * DD,
        zb, rhb, t1b, N);
    agg1_k<<<aggBlocks, 256, 0, stream>>>(rhb, offsets, csr_src, dinv, Arh, N);
    const int doPack = (l + 1 < L);
    out4_k<<<dBlocks, 256, 0, stream>>>(Arh, t1b, zb, Hh, Whh + (size_t)l * DD * DD,
        out + (size_t)l * ND, out + (size_t)L * ND + (size_t)l * ND,
        h + (size_t)(l + 1 < L ? l + 1 : l) * ND, XH, doPack, N);
  }
}

// Round 8
// 626.993 us; speedup vs baseline: 2.6977x; 1.3101x over previous
//
#include <hip/hip_runtime.h>
#include <hip/hip_fp16.h>
#include <math.h>
#include <stdint.h>

#define DD 64
#define CHUNK 1024

using f16x8 = __attribute__((ext_vector_type(8))) _Float16;
using f32x4 = __attribute__((ext_vector_type(4))) float;

static inline int divup(int a, int b){ return (a + b - 1) / b; }

// --- histogram, 4 edges/thread; col atomic's return = edge rank in column ---
__global__ void hist4_k(const int* __restrict__ edg, int* __restrict__ rowcnt,
                        int* __restrict__ colcnt, int* __restrict__ rank, int E4){
  int i = blockIdx.x * 256 + threadIdx.x;
  if (i < E4){
    int4 r4 = ((const int4*)edg)[i];
    int4 c4 = ((const int4*)(edg))[E4 + i];
    atomicAdd(&rowcnt[r4.x], 1);
    atomicAdd(&rowcnt[r4.y], 1);
    atomicAdd(&rowcnt[r4.z], 1);
    atomicAdd(&rowcnt[r4.w], 1);
    int4 k4;
    k4.x = atomicAdd(&colcnt[c4.x], 1);
    k4.y = atomicAdd(&colcnt[c4.y], 1);
    k4.z = atomicAdd(&colcnt[c4.z], 1);
    k4.w = atomicAdd(&colcnt[c4.w], 1);
    ((int4*)rank)[i] = k4;
  }
}

__global__ void hist_k(const int* __restrict__ edg, int* __restrict__ rowcnt,
                       int* __restrict__ colcnt, int* __restrict__ rank, int E){
  int e = blockIdx.x * 256 + threadIdx.x;
  if (e < E){
    atomicAdd(&rowcnt[edg[e]], 1);
    rank[e] = atomicAdd(&colcnt[edg[E + e]], 1);
  }
}

// --- scan pass 1 (block sums) + fused dinv = (rowcnt+2)^-1/2 ---
__global__ void scan1_k(const int* __restrict__ cnt, const int* __restrict__ rowcnt,
                        float* __restrict__ dinv, int* __restrict__ bsum, int N){
  __shared__ int sh[256];
  int t = threadIdx.x;
  int base = blockIdx.x * CHUNK + t * 4;
  int s = 0;
  #pragma unroll
  for (int j = 0; j < 4; j++){
    int g = base + j;
    if (g < N){
      s += cnt[g];
      dinv[g] = 1.0f / sqrtf((float)rowcnt[g] + 2.0f);
    }
  }
  sh[t] = s; __syncthreads();
  for (int off = 128; off > 0; off >>= 1){
    if (t < off) sh[t] += sh[t + off];
    __syncthreads();
  }
  if (t == 0) bsum[blockIdx.x] = sh[0];
}

__global__ void scan2_k(const int* __restrict__ bsum, int* __restrict__ bpre, int NB){
  __shared__ int sh[128];
  int t = threadIdx.x;
  int v = (t < NB) ? bsum[t] : 0;
  sh[t] = v; __syncthreads();
  for (int off = 1; off < 128; off <<= 1){
    int x = (t >= off) ? sh[t - off] : 0;
    __syncthreads();
    sh[t] += x;
    __syncthreads();
  }
  if (t < NB) bpre[t] = sh[t] - v;
}

__global__ void scan3_k(const int* __restrict__ cnt, const int* __restrict__ bpre,
                        int* __restrict__ offsets, int N){
  __shared__ int sh[256];
  int t = threadIdx.x, b = blockIdx.x;
  int base = b * CHUNK + t * 4;
  int v[4]; int s = 0;
  #pragma unroll
  for (int j = 0; j < 4; j++){ int g = base + j; v[j] = (g < N) ? cnt[g] : 0; s += v[j]; }
  sh[t] = s; __syncthreads();
  for (int off = 1; off < 256; off <<= 1){
    int x = (t >= off) ? sh[t - off] : 0;
    __syncthreads();
    sh[t] += x;
    __syncthreads();
  }
  int run = sh[t] - s + bpre[b];
  #pragma unroll
  for (int j = 0; j < 4; j++){
    int g = base + j;
    if (g <= N) offsets[g] = run;
    run += v[j];
  }
}

// --- atomic-free scatter, 4 edges/thread ---
__global__ void scatter4_k(const int* __restrict__ edg, const int* __restrict__ offsets,
                           const int* __restrict__ rank, int* __restrict__ csr_src, int E4){
  int i = blockIdx.x * 256 + threadIdx.x;
  if (i < E4){
    int4 r4 = ((const int4*)edg)[i];
    int4 c4 = ((const int4*)(edg))[E4 + i];
    int4 k4 = ((const int4*)rank)[i];
    csr_src[offsets[c4.x] + k4.x] = r4.x;
    csr_src[offsets[c4.y] + k4.y] = r4.y;
    csr_src[offsets[c4.z] + k4.z] = r4.z;
    csr_src[offsets[c4.w] + k4.w] = r4.w;
  }
}

__global__ void scatter_k(const int* __restrict__ edg, const int* __restrict__ offsets,
                          const int* __restrict__ rank, int* __restrict__ csr_src, int E){
  int e = blockIdx.x * 256 + threadIdx.x;
  if (e < E){
    csr_src[offsets[edg[E + e]] + rank[e]] = edg[e];
  }
}

// --- pack layer-0 gather matrix: XH[node][j] = (half(x), half(h)) ---
__global__ void pack0_k(const float* __restrict__ X, const float* __restrict__ H,
                        __half2* __restrict__ XH, int total){
  int i = blockIdx.x * 256 + threadIdx.x;
  if (i < total){
    __half2 v;
    v.x = __float2half_rn(X[i]);
    v.y = __float2half_rn(H[i]);
    XH[i] = v;
  }
}

// --- pack weights into MFMA B-fragment order (both layers) + fused biases ---
// Bg[l][jt(12)][ks(4)][lane(64)][s(8)]: j-blocks 0..3=z, 4..7=r, 8..11=t1.
//   k = ks*32 + (lane>>4)*8 + s (0..127; k<64 -> Wx row k, k>=64 -> Wh row k-64)
//   j = (jt&3)*16 + (lane&15)
// Bo[l][jt(4)][ks(2)][lane][s]: Whh[k][j], k = ks*32+(lane>>4)*8+s, j = jt*16+(lane&15)
// biasg[l][192]: 0..63 bxz+bhz, 64..127 bxr+bhr, 128..191 bxh+bhh
__global__ void packb_k(const float* __restrict__ Wxz, const float* __restrict__ Whz,
                        const float* __restrict__ Wxr, const float* __restrict__ Whr,
                        const float* __restrict__ Wxh, const float* __restrict__ Whh,
                        const float* __restrict__ bxz, const float* __restrict__ bhz,
                        const float* __restrict__ bxr, const float* __restrict__ bhr,
                        const float* __restrict__ bxh, const float* __restrict__ bhh,
                        _Float16* __restrict__ Bg, _Float16* __restrict__ Bo,
                        float* __restrict__ biasg, int L){
  const int PER = 24576 + 4096 + 192;
  int tid = blockIdx.x * 256 + threadIdx.x;
  if (tid >= L * PER) return;
  int l = tid / PER, r = tid % PER;
  if (r < 24576){
    int q = r;
    int s = q & 7, lane = (q >> 3) & 63, ks = (q >> 9) & 3, jt = q >> 11;
    int k = ks * 32 + (lane >> 4) * 8 + s;
    int b = jt >> 2;
    int j = (jt & 3) * 16 + (lane & 15);
    const float* Wx = (b == 0) ? Wxz : (b == 1) ? Wxr : Wxh;
    const float* Wh = (b == 0) ? Whz : Whr;
    float v;
    if (k < 64) v = Wx[(size_t)l * 4096 + k * 64 + j];
    else        v = (b == 2) ? 0.0f : Wh[(size_t)l * 4096 + (k - 64) * 64 + j];
    Bg[(size_t)l * 24576 + q] = (_Float16)v;
  } else if (r < 24576 + 4096){
    int q = r - 24576;
    int s = q & 7, lane = (q >> 3) & 63, ks = (q >> 9) & 1, jt = q >> 10;
    int k = ks * 32 + (lane >> 4) * 8 + s;
    int j = jt * 16 + (lane & 15);
    Bo[(size_t)l * 4096 + q] = (_Float16)Whh[(size_t)l * 4096 + k * 64 + j];
  } else {
    int j = r - (24576 + 4096);
    int b = j >> 6, jj = j & 63;
    float v = (b == 0) ? bxz[l * 64 + jj] + bhz[l * 64 + jj]
            : (b == 1) ? bxr[l * 64 + jj] + bhr[l * 64 + jj]
                       : bxh[l * 64 + jj] + bhh[l * 64 + jj];
    biasg[l * 192 + j] = v;
  }
}

// --- fused aggregation of (x,h) fp16 pairs, unroll 4; writes AXAH fp16 [node][128] ---
__global__ void agg2_k(const __half2* __restrict__ XH,
                       const int* __restrict__ offsets, const int* __restrict__ src,
                       const float* __restrict__ dinv,
                       _Float16* __restrict__ AXAH, int N){
  int wid = (blockIdx.x * blockDim.x + threadIdx.x) >> 6;
  int lane = threadIdx.x & 63;
  if (wid >= N) return;
  float dv = dinv[wid];
  float selfw = 2.0f * dv * dv;
  size_t me = (size_t)wid * DD + lane;
  float2 sf = __half22float2(XH[me]);
  float ax1 = selfw * sf.x, ah1 = selfw * sf.y;
  float ax2 = 0.0f, ah2 = 0.0f;
  float ax3 = 0.0f, ah3 = 0.0f;
  float ax4 = 0.0f, ah4 = 0.0f;
  int s0 = offsets[wid], s1 = offsets[wid + 1];
  int e = s0;
  for (; e + 4 <= s1; e += 4){
    int sa = src[e], sb = src[e + 1], sc = src[e + 2], sd = src[e + 3];
    float wa = dinv[sa] * dv, wb = dinv[sb] * dv;
    float wc = dinv[sc] * dv, wd = dinv[sd] * dv;
    float2 fa = __half22float2(XH[(size_t)sa * DD + lane]);
    float2 fb = __half22float2(XH[(size_t)sb * DD + lane]);
    float2 fc = __half22float2(XH[(size_t)sc * DD + lane]);
    float2 fd = __half22float2(XH[(size_t)sd * DD + lane]);
    ax1 += wa * fa.x;  ah1 += wa * fa.y;
    ax2 += wb * fb.x;  ah2 += wb * fb.y;
    ax3 += wc * fc.x;  ah3 += wc * fc.y;
    ax4 += wd * fd.x;  ah4 += wd * fd.y;
  }
  for (; e < s1; ++e){
    int sa = src[e];
    float wa = dinv[sa] * dv;
    float2 fa = __half22float2(XH[(size_t)sa * DD + lane]);
    ax1 += wa * fa.x;
    ah1 += wa * fa.y;
  }
  size_t o = (size_t)wid * 128 + lane;
  AXAH[o]      = (_Float16)((ax1 + ax2) + (ax3 + ax4));
  AXAH[o + 64] = (_Float16)((ah1 + ah2) + (ah3 + ah4));
}

// --- aggregation of fp16 rows (r*h), unroll 4; writes Arh fp16 [node][64] ---
__global__ void agg1_k(const _Float16* __restrict__ RH,
                       const int* __restrict__ offsets, const int* __restrict__ src,
                       const float* __restrict__ dinv,
                       _Float16* __restrict__ Arh, int N){
  int wid = (blockIdx.x * blockDim.x + threadIdx.x) >> 6;
  int lane = threadIdx.x & 63;
  if (wid >= N) return;
  float dv = dinv[wid];
  float selfw = 2.0f * dv * dv;
  size_t me = (size_t)wid * DD + lane;
  float ax1 = selfw * (float)RH[me];
  float ax2 = 0.0f, ax3 = 0.0f, ax4 = 0.0f;
  int s0 = offsets[wid], s1 = offsets[wid + 1];
  int e = s0;
  for (; e + 4 <= s1; e += 4){
    int sa = src[e], sb = src[e + 1], sc = src[e + 2], sd = src[e + 3];
    float wa = dinv[sa] * dv, wb = dinv[sb] * dv;
    float wc = dinv[sc] * dv, wd = dinv[sd] * dv;
    ax1 += wa * (float)RH[(size_t)sa * DD + lane];
    ax2 += wb * (float)RH[(size_t)sb * DD + lane];
    ax3 += wc * (float)RH[(size_t)sc * DD + lane];
    ax4 += wd * (float)RH[(size_t)sd * DD + lane];
  }
  for (; e < s1; ++e){
    ax1 += (dinv[src[e]] * dv) * (float)RH[(size_t)src[e] * DD + lane];
  }
  Arh[me] = (_Float16)((ax1 + ax2) + (ax3 + ax4));
}

// ---------------------------------------------------------------------------
// MFMA gate kernel: C(N x 192) = AXAH(N x 128) @ Bg(128 x 192) + bias.
// Wave = 32 nodes (2 M-tiles) x 12 N-tiles, K-steps = 4. acc layout per m89:
// col = lane&15, row_in_tile = (lane>>4)*4 + i.
// Epilogue: z = sigmoid -> zb(fp16); rh = h*sigmoid(r) -> rhb(fp16); t1 -> t1b(fp16).
// ---------------------------------------------------------------------------
__global__ __launch_bounds__(256) void gatem_k(
    const _Float16* __restrict__ AXAH, const float* __restrict__ Hh,
    const _Float16* __restrict__ Bg, const float* __restrict__ biasg,
    _Float16* __restrict__ zb, _Float16* __restrict__ rhb,
    _Float16* __restrict__ t1b, int N)
{
  const int lane = threadIdx.x & 63;
  const int wv   = threadIdx.x >> 6;
  const long nbase = ((long)blockIdx.x * 4 + wv) * 32;
  if (nbase >= N) return;
  const int m  = lane & 15;
  const int kb = lane >> 4;

  f32x4 acc[2][12];
  #pragma unroll
  for (int jt = 0; jt < 12; jt++){
    float bv = biasg[jt * 16 + m];
    f32x4 b4 = {bv, bv, bv, bv};
    acc[0][jt] = b4;
    acc[1][jt] = b4;
  }

  #pragma unroll 1
  for (int ks = 0; ks < 4; ks++){
    f16x8 af0, af1;
    {
      long r0 = nbase + m;           if (r0 >= N) r0 = N - 1;
      long r1 = nbase + 16 + m;      if (r1 >= N) r1 = N - 1;
      af0 = *(const f16x8*)(AXAH + (size_t)r0 * 128 + ks * 32 + kb * 8);
      af1 = *(const f16x8*)(AXAH + (size_t)r1 * 128 + ks * 32 + kb * 8);
    }
    #pragma unroll
    for (int jt = 0; jt < 12; jt++){
      f16x8 bf = *(const f16x8*)(Bg + ((size_t)(jt * 4 + ks) * 64 + lane) * 8);
      acc[0][jt] = __builtin_amdgcn_mfma_f32_16x16x32_f16(af0, bf, acc[0][jt], 0, 0, 0);
      acc[1][jt] = __builtin_amdgcn_mfma_f32_16x16x32_f16(af1, bf, acc[1][jt], 0, 0, 0);
    }
  }

  #pragma unroll
  for (int mt = 0; mt < 2; mt++){
    #pragma unroll
    for (int i = 0; i < 4; i++){
      long row = nbase + mt * 16 + kb * 4 + i;
      if (row < N){
        #pragma unroll
        for (int jq = 0; jq < 4; jq++){
          int j = jq * 16 + m;
          size_t o = (size_t)row * 64 + j;
          float zpre = acc[mt][jq][i];
          float rpre = acc[mt][4 + jq][i];
          float t1v  = acc[mt][8 + jq][i];
          float hv = Hh[o];
          zb[o]  = (_Float16)(1.0f / (1.0f + __expf(-zpre)));
          rhb[o] = (_Float16)(hv / (1.0f + __expf(-rpre)));
          t1b[o] = (_Float16)t1v;
        }
      }
    }
  }
}

// ---------------------------------------------------------------------------
// MFMA output kernel: acc = t1 (C-init) + Arh(N x 64) @ Bo(64 x 64);
// h_t = tanh(acc); ho = z*h + (1-z)*h_t -> o1, o2, optional XHnext pack.
// ---------------------------------------------------------------------------
__global__ __launch_bounds__(256) void outm_k(
    const _Float16* __restrict__ Arh, const _Float16* __restrict__ t1b,
    const _Float16* __restrict__ zb, const float* __restrict__ Hh,
    const _Float16* __restrict__ Bo,
    float* __restrict__ o1, float* __restrict__ o2,
    const float* __restrict__ hNext, __half2* __restrict__ XHnext,
    int doPack, int N)
{
  const int lane = threadIdx.x & 63;
  const int wv   = threadIdx.x >> 6;
  const long nbase = ((long)blockIdx.x * 4 + wv) * 32;
  if (nbase >= N) return;
  const int m  = lane & 15;
  const int kb = lane >> 4;

  f32x4 acc[2][4];
  #pragma unroll
  for (int mt = 0; mt < 2; mt++){
    #pragma unroll
    for (int jt = 0; jt < 4; jt++){
      #pragma unroll
      for (int i = 0; i < 4; i++){
        long row = nbase + mt * 16 + kb * 4 + i;
        if (row >= N) row = N - 1;
        acc[mt][jt][i] = (float)t1b[(size_t)row * 64 + jt * 16 + m];
      }
    }
  }

  #pragma unroll
  for (int ks = 0; ks < 2; ks++){
    f16x8 af0, af1;
    {
      long r0 = nbase + m;           if (r0 >= N) r0 = N - 1;
      long r1 = nbase + 16 + m;      if (r1 >= N) r1 = N - 1;
      af0 = *(const f16x8*)(Arh + (size_t)r0 * 64 + ks * 32 + kb * 8);
      af1 = *(const f16x8*)(Arh + (size_t)r1 * 64 + ks * 32 + kb * 8);
    }
    #pragma unroll
    for (int jt = 0; jt < 4; jt++){
      f16x8 bf = *(const f16x8*)(Bo + ((size_t)(jt * 2 + ks) * 64 + lane) * 8);
      acc[0][jt] = __builtin_amdgcn_mfma_f32_16x16x32_f16(af0, bf, acc[0][jt], 0, 0, 0);
      acc[1][jt] = __builtin_amdgcn_mfma_f32_16x16x32_f16(af1, bf, acc[1][jt], 0, 0, 0);
    }
  }

  #pragma unroll
  for (int mt = 0; mt < 2; mt++){
    #pragma unroll
    for (int i = 0; i < 4; i++){
      long row = nbase + mt * 16 + kb * 4 + i;
      if (row < N){
        #pragma unroll
        for (int jt = 0; jt < 4; jt++){
          int j = jt * 16 + m;
          size_t o = (size_t)row * 64 + j;
          float e = __expf(2.0f * acc[mt][jt][i]);
          float ht = 1.0f - 2.0f / (e + 1.0f);
          float z = (float)zb[o];
          float hv = Hh[o];
          float ho = z * hv + (1.0f - z) * ht;
          o1[o] = ho;
          o2[o] = ho;
          if (doPack){
            __half2 v;
            v.x = __float2half_rn(ho);
            v.y = __float2half_rn(hNext[o]);
            XHnext[o] = v;
          }
        }
      }
    }
  }
}

extern "C" void kernel_launch(void* const* d_in, const int* in_sizes, int n_in,
                              void* d_out, int out_size, void* d_ws, size_t ws_size,
                              hipStream_t stream){
  const float* inp = (const float*)d_in[0];
  const float* h   = (const float*)d_in[1];
  const int*   edg = (const int*)d_in[2];
  const float* Wxz = (const float*)d_in[3];
  const float* Whz = (const float*)d_in[4];
  const float* Wxr = (const float*)d_in[5];
  const float* Whr = (const float*)d_in[6];
  const float* Wxh = (const float*)d_in[7];
  const float* Whh = (const float*)d_in[8];
  const float* bxz = (const float*)d_in[9];
  const float* bhz = (const float*)d_in[10];
  const float* bxr = (const float*)d_in[11];
  const float* bhr = (const float*)d_in[12];
  const float* bxh = (const float*)d_in[13];
  const float* bhh = (const float*)d_in[14];
  float* out = (float*)d_out;

  const int ND = in_sizes[0];
  const int N  = ND / DD;
  const int E  = in_sizes[2] / 2;
  const int L  = in_sizes[1] / ND;

  char* p = (char*)d_ws;
  auto alloc = [&](size_t bytes) -> void* {
    void* r = (void*)p;
    p += ((bytes + 255) / 256) * 256;
    return r;
  };
  int*      rowcnt  = (int*)alloc((size_t)2 * N * 4);   // rowcnt | colcnt
  int*      colcnt  = rowcnt + N;
  int*      offsets = (int*)alloc((size_t)(N + 1) * 4);
  int*      bsum    = (int*)alloc(128 * 4);
  int*      bpre    = (int*)alloc(128 * 4);
  float*    dinv    = (float*)alloc((size_t)N * 4);
  int*      rank    = (int*)alloc((size_t)E * 4);
  int*      csr_src = (int*)alloc((size_t)E * 4);
  __half2*  XH      = (__half2*)alloc((size_t)ND * 4);      // (x,h) fp16 pairs
  _Float16* AXAH    = (_Float16*)alloc((size_t)N * 128 * 2);// [ax|ah] fp16
  _Float16* Arh     = (_Float16*)alloc((size_t)ND * 2);
  _Float16* zb      = (_Float16*)alloc((size_t)ND * 2);
  _Float16* t1b     = (_Float16*)alloc((size_t)ND * 2);
  _Float16* rhb     = (_Float16*)alloc((size_t)ND * 2);
  _Float16* Bg      = (_Float16*)alloc((size_t)L * 24576 * 2);
  _Float16* Bo      = (_Float16*)alloc((size_t)L * 4096 * 2);
  float*    biasg   = (float*)alloc((size_t)L * 192 * 4);

  hipMemsetAsync(rowcnt, 0, (size_t)2 * N * 4, stream);

  const int NB = divup(N, CHUNK);
  if ((E & 3) == 0){
    const int E4 = E / 4;
    hist4_k<<<divup(E4, 256), 256, 0, stream>>>(edg, rowcnt, colcnt, rank, E4);
  } else {
    hist_k<<<divup(E, 256), 256, 0, stream>>>(edg, rowcnt, colcnt, rank, E);
  }
  scan1_k<<<NB, 256, 0, stream>>>(colcnt, rowcnt, dinv, bsum, N);
  scan2_k<<<1, 128, 0, stream>>>(bsum, bpre, NB);
  scan3_k<<<NB, 256, 0, stream>>>(colcnt, bpre, offsets, N);
  if ((E & 3) == 0){
    const int E4 = E / 4;
    scatter4_k<<<divup(E4, 256), 256, 0, stream>>>(edg, offsets, rank, csr_src, E4);
  } else {
    scatter_k<<<divup(E, 256), 256, 0, stream>>>(edg, offsets, rank, csr_src, E);
  }
  pack0_k<<<divup(ND, 256), 256, 0, stream>>>(inp, h, XH, ND);
  {
    const int PER = 24576 + 4096 + 192;
    packb_k<<<divup(L * PER, 256), 256, 0, stream>>>(
        Wxz, Whz, Wxr, Whr, Wxh, Whh,
        bxz, bhz, bxr, bhr, bxh, bhh, Bg, Bo, biasg, L);
  }

  const int aggBlocks = divup(N, 4);     // 4 waves (nodes) per 256-thread block
  const int mBlocks   = divup(N, 128);   // 4 waves x 32 nodes per block

  for (int l = 0; l < L; l++){
    const float* Hh = h + (size_t)l * ND;
    agg2_k<<<aggBlocks, 256, 0, stream>>>(XH, offsets, csr_src, dinv, AXAH, N);
    gatem_k<<<mBlocks, 256, 0, stream>>>(AXAH, Hh,
        Bg + (size_t)l * 24576, biasg + (size_t)l * 192, zb, rhb, t1b, N);
    agg1_k<<<aggBlocks, 256, 0, stream>>>(rhb, offsets, csr_src, dinv, Arh, N);
    const int doPack = (l + 1 < L);
    outm_k<<<mBlocks, 256, 0, stream>>>(Arh, t1b, zb, Hh,
        Bo + (size_t)l * 4096,
        out + (size_t)l * ND, out + (size_t)L * ND + (size_t)l * ND,
        h + (size_t)(l + 1 < L ? l + 1 : l) * ND, XH, doPack, N);
  }
}